// Round 11
// baseline (265.745 us; speedup 1.0000x reference)
//
#include <hip/hip_runtime.h>
#include <math.h>

// Problem constants (B=4, S=1024, E=512, H=8, D=64, T_MAX=20)
#define SEQ   1024
#define EMB   512
#define NROWS 4096   // B*S
#define LDP   72     // attn LDS row stride (bf16 elems)
#define GROWS 4      // gates rows per block

typedef __attribute__((ext_vector_type(8))) short short8;    // bf16 x8 MFMA frag
typedef __attribute__((ext_vector_type(4))) float float4v;   // f32 x4 MFMA acc

__device__ __forceinline__ float bf2f(unsigned short s) {
    union { float f; unsigned u; } x; x.u = ((unsigned)s) << 16; return x.f;
}
__device__ __forceinline__ unsigned short f2bf(float f) {
    union { float f; unsigned u; } x; x.f = f;
    unsigned r = x.u + 0x7fffu + ((x.u >> 16) & 1u);   // round-to-nearest-even
    return (unsigned short)(r >> 16);
}

// async global->LDS 16B: LDS dest = wave-uniform base + lane*16 (HW rule).
__device__ __forceinline__ void gld16(const unsigned short* g, short* l) {
    __builtin_amdgcn_global_load_lds(
        (__attribute__((address_space(1))) void*)(g),
        (__attribute__((address_space(3))) void*)(l), 16, 0, 0);
}

// 3-limb bf16 split: x ~= h + m + l. Residual subtractions are Sterbenz-exact,
// so h+m+l carries ~26 mantissa bits of x; per-limb repr error <= 2^-27 |x|.
__device__ __forceinline__ void split3(float x, unsigned short& h, unsigned short& m, unsigned short& l) {
    union { float f; unsigned u; } a; a.f = x;
    const unsigned rh = a.u + 0x7fffu + ((a.u >> 16) & 1u);
    h = (unsigned short)(rh >> 16);
    union { float f; unsigned u; } hf; hf.u = rh & 0xffff0000u;
    const float r1 = x - hf.f;                 // exact
    a.f = r1;
    const unsigned rm = a.u + 0x7fffu + ((a.u >> 16) & 1u);
    m = (unsigned short)(rm >> 16);
    union { float f; unsigned u; } mf; mf.u = rm & 0xffff0000u;
    const float r2 = r1 - mf.f;                // exact
    l = f2bf(r2);
}

// ---------------------------------------------------------------------------
// gate/complexity MLP evaluator. R11: xs stored as f32 (input IS f32; f64
// conversion happens exactly at the point of use -> every f64 operation sees
// identical operands -> bit-identical results). Halves GEMM1's LDS read
// bytes and shrinks the arena 30.8->22.6 KB (5->7 blocks/CU).
// ---------------------------------------------------------------------------
template<int H1, int H2>
__device__ __forceinline__ double mlp_eval(
    const float xs[GROWS][EMB], double* h1, double* h2, double* red,
    double* mu_s, double* var_s,
    const float* __restrict__ W1, const float* __restrict__ b1,
    const float* __restrict__ gam, const float* __restrict__ bet,
    const float* __restrict__ W2, const float* __restrict__ b2,
    const float* __restrict__ W3, const float* __restrict__ b3,
    int tid, int myrow)
{
    constexpr int S  = 256 / H1;    // k-slices: 2 (gate), 4 (complexity)
    constexpr int KS = EMB / S;     // 256 or 128

    {   // h1 partials: thread = (col, k-slice), 4-row ILP (1 W1 load -> 4 FMAs)
        const int col = tid % H1, sk = tid / H1;
        double acc[GROWS] = {0.0, 0.0, 0.0, 0.0};
        const int kbeg = sk * KS;
        #pragma unroll 4
        for (int k = kbeg; k < kbeg + KS; ++k) {
            const double w = (double)W1[k * H1 + col];
            #pragma unroll
            for (int r = 0; r < GROWS; ++r) acc[r] += w * (double)xs[r][k];
        }
        #pragma unroll
        for (int r = 0; r < GROWS; ++r) red[(sk * GROWS + r) * H1 + col] = acc[r];
    }
    __syncthreads();
    for (int idx = tid; idx < GROWS * H1; idx += 256) {   // reduce + bias
        const int r = idx / H1, cc = idx % H1;
        double s = 0.0;
        #pragma unroll
        for (int t = 0; t < S; ++t) s += red[(t * GROWS + r) * H1 + cc];
        h1[r * H1 + cc] = s + (double)b1[cc];
    }
    __syncthreads();

    {   // mean: wave w owns row w
        const int w = tid >> 6, l = tid & 63;
        double s = 0.0;
        for (int c = l; c < H1; c += 64) s += h1[w * H1 + c];
        #pragma unroll
        for (int off = 32; off >= 1; off >>= 1) s += __shfl_xor(s, off);
        if (l == 0) mu_s[w] = s / (double)H1;
    }
    __syncthreads();
    {   // var
        const int w = tid >> 6, l = tid & 63;
        const double mu = mu_s[w];
        double s = 0.0;
        for (int c = l; c < H1; c += 64) { const double d = h1[w * H1 + c] - mu; s += d * d; }
        #pragma unroll
        for (int off = 32; off >= 1; off >>= 1) s += __shfl_xor(s, off);
        if (l == 0) var_s[w] = s / (double)H1;
    }
    __syncthreads();
    // normalize + relu
    for (int idx = tid; idx < GROWS * H1; idx += 256) {
        const int r = idx / H1, cc = idx % H1;
        double hn = (h1[r * H1 + cc] - mu_s[r]) / sqrt(var_s[r] + 1e-5) * (double)gam[cc] + (double)bet[cc];
        h1[r * H1 + cc] = hn > 0.0 ? hn : 0.0;
    }
    __syncthreads();

    {   // h2 = relu(h1 @ W2 + b2)
        const int col = tid % H2;
        const int r   = tid / H2;
        if (r < GROWS) {
            double acc = (double)b2[col];
            for (int k = 0; k < H1; ++k)
                acc += (double)W2[k * H2 + col] * h1[r * H1 + k];
            h2[r * H2 + col] = acc > 0.0 ? acc : 0.0;
        }
    }
    __syncthreads();

    {   // scalar = h2 @ W3: wave w owns row w
        const int w = tid >> 6, l = tid & 63;
        double s = 0.0;
        for (int c = l; c < H2; c += 64) s += h2[w * H2 + c] * (double)W3[c];
        #pragma unroll
        for (int off = 32; off >= 1; off >>= 1) s += __shfl_xor(s, off);
        if (l == 0) mu_s[w] = s;   // reuse as scratch
    }
    __syncthreads();
    double ret = 0.0;
    if (myrow >= 0) {
        const double z = mu_s[myrow] + (double)b3[0];
        ret = 1.0 / (1.0 + exp(-z));
    }
    return ret;
}

// ---------------------------------------------------------------------------
// K0: fused pre-kernel: gates / x_limbs / w_limbs / wot. Arena 22.6 KB.
// ---------------------------------------------------------------------------
__global__ __launch_bounds__(256) void pre_kernel(
    const float* __restrict__ x,
    const float* __restrict__ gW1, const float* __restrict__ gb1,
    const float* __restrict__ gg,  const float* __restrict__ gbe,
    const float* __restrict__ gW2, const float* __restrict__ gb2,
    const float* __restrict__ gW3, const float* __restrict__ gb3,
    const float* __restrict__ cW1, const float* __restrict__ cb1,
    const float* __restrict__ cg,  const float* __restrict__ cbe,
    const float* __restrict__ cW2, const float* __restrict__ cb2,
    const float* __restrict__ cW3, const float* __restrict__ cb3,
    double* __restrict__ scores,
    const float* __restrict__ Wq, const float* __restrict__ Wk,
    const float* __restrict__ Wv, unsigned short* __restrict__ WL,
    unsigned short* __restrict__ XL,
    const float* __restrict__ Wo, unsigned short* __restrict__ WoT)
{
    __shared__ __align__(16) char smem[22592];
    const int bid = blockIdx.x;
    const int tid = threadIdx.x;

    if (bid < 2048) {
        // ---- gates ----
        float (*xs)[EMB] = (float(*)[EMB])smem;              // 8192 B (f32)
        double* h1    = (double*)(smem + 8192);              // 4096 B
        double* h2    = (double*)(smem + 12288);             // 2048 B
        double* red   = (double*)(smem + 14336);             // 8192 B
        double* mu_s  = (double*)(smem + 22528);
        double* var_s = (double*)(smem + 22560);

        const int gx = bid & 1023, gy = bid >> 10;
        const int row0 = gx * GROWS;

        // rows are contiguous -> flat float4 copy of 2048 f32
        {
            const float4* src = (const float4*)&x[(size_t)row0 * EMB];
            float4* dst = (float4*)smem;
            for (int idx = tid; idx < GROWS * EMB / 4; idx += 256)
                dst[idx] = src[idx];
        }
        __syncthreads();

        const int myrow = (tid < GROWS) ? tid : -1;
        double v;
        if (gy == 0)
            v = mlp_eval<128, 64>(xs, h1, h2, red, mu_s, var_s,
                                  gW1, gb1, gg, gbe, gW2, gb2, gW3, gb3, tid, myrow);
        else
            v = mlp_eval<64, 32>(xs, h1, h2, red, mu_s, var_s,
                                 cW1, cb1, cg, cbe, cW2, cb2, cW3, cb3, tid, myrow);

        if (myrow >= 0)
            scores[(size_t)gy * NROWS + row0 + myrow] = v;

    } else if (bid < 3072) {
        // ---- x limb prep ----
        unsigned short* Xh = XL;
        unsigned short* Xm = XL + (size_t)NROWS * EMB;
        unsigned short* Xl = Xm + (size_t)NROWS * EMB;
        const size_t i0 = ((size_t)(bid - 2048) * 256 + tid) * 8;
        const float4 a0 = *(const float4*)&x[i0];
        const float4 a1 = *(const float4*)&x[i0 + 4];
        const float av8[8] = {a0.x, a0.y, a0.z, a0.w, a1.x, a1.y, a1.z, a1.w};
        short8 ph, pm, pl;
        #pragma unroll
        for (int e = 0; e < 8; ++e) {
            unsigned short h, m, l;
            split3(av8[e], h, m, l);
            ph[e] = (short)h; pm[e] = (short)m; pl[e] = (short)l;
        }
        *(short8*)&Xh[i0] = ph;
        *(short8*)&Xm[i0] = pm;
        *(short8*)&Xl[i0] = pl;

    } else if (bid < 3264) {
        // ---- W^T limb prep ----
        const int t = bid - 3072;
        const int z = t >> 6, rem = t & 63;
        const int k0 = (rem >> 3) * 64, n0 = (rem & 7) * 64;
        const float* __restrict__ W = (z == 0) ? Wq : (z == 1) ? Wk : Wv;
        unsigned short* Th = WL + (size_t)z * 3 * EMB * EMB;
        unsigned short* Tm = Th + (size_t)EMB * EMB;
        unsigned short* Tl = Tm + (size_t)EMB * EMB;

        float (*Ws)[68] = (float(*)[68])smem;   // 17408 B
        #pragma unroll
        for (int it = 0; it < 4; ++it) {
            const int idx = it * 256 + tid;
            const int r = idx >> 4, c4 = (idx & 15) * 4;
            *(float4*)&Ws[r][c4] = *(const float4*)&W[(size_t)(k0 + r) * EMB + n0 + c4];
        }
        __syncthreads();
        #pragma unroll
        for (int it = 0; it < 2; ++it) {
            const int idx = it * 256 + tid;
            const int n = idx >> 3, k8 = (idx & 7) * 8;
            short8 ph, pm, pl;
            #pragma unroll
            for (int j = 0; j < 8; ++j) {
                unsigned short h, m, l;
                split3(Ws[k8 + j][n], h, m, l);
                ph[j] = (short)h; pm[j] = (short)m; pl[j] = (short)l;
            }
            const size_t o = (size_t)(n0 + n) * EMB + k0 + k8;
            *(short8*)&Th[o] = ph;
            *(short8*)&Tm[o] = pm;
            *(short8*)&Tl[o] = pl;
        }

    } else {
        // ---- Wo^T bf16 prep ----
        const int t = bid - 3264;
        const int k0 = (t >> 3) * 64, n0 = (t & 7) * 64;
        unsigned short (*Ws)[72] = (unsigned short(*)[72])smem;   // 9216 B
        #pragma unroll
        for (int it = 0; it < 4; ++it) {
            const int idx = it * 256 + tid;
            const int r = idx >> 4, c4 = (idx & 15) * 4;
            const float4 w4 = *(const float4*)&Wo[(size_t)(k0 + r) * EMB + n0 + c4];
            Ws[r][c4 + 0] = f2bf(w4.x); Ws[r][c4 + 1] = f2bf(w4.y);
            Ws[r][c4 + 2] = f2bf(w4.z); Ws[r][c4 + 3] = f2bf(w4.w);
        }
        __syncthreads();
        #pragma unroll
        for (int it = 0; it < 2; ++it) {
            const int idx = it * 256 + tid;
            const int n = idx >> 3, k8 = (idx & 7) * 8;
            short8 pack;
            #pragma unroll
            for (int j = 0; j < 8; ++j) pack[j] = (short)Ws[k8 + j][n];
            *(short8*)&WoT[(size_t)(n0 + n) * EMB + k0 + k8] = pack;
        }
    }
}

// ---------------------------------------------------------------------------
// K1: QKV GEMM, 3-limb split-bf16 MFMA (R6/R9 body, unchanged).
// ---------------------------------------------------------------------------
__global__ __launch_bounds__(256) void qkv_mfma_lif_kernel(
    const unsigned short* __restrict__ XL, const unsigned short* __restrict__ WL,
    const float* __restrict__ aq, const float* __restrict__ bq,
    const float* __restrict__ akp, const float* __restrict__ bkp,
    const float* __restrict__ av, const float* __restrict__ bv,
    const double* __restrict__ scores,
    unsigned short* __restrict__ q_sum, unsigned short* __restrict__ k_sum,
    unsigned short* __restrict__ v_mean)
{
    const int z = blockIdx.z;
    const unsigned short* __restrict__ WTh = WL + (size_t)z * 3 * EMB * EMB;
    const unsigned short* __restrict__ WTm = WTh + (size_t)EMB * EMB;
    const unsigned short* __restrict__ WTl = WTm + (size_t)EMB * EMB;
    const unsigned short* __restrict__ Xh = XL;
    const unsigned short* __restrict__ Xm = XL + (size_t)NROWS * EMB;
    const unsigned short* __restrict__ Xl = Xm + (size_t)NROWS * EMB;
    unsigned short* __restrict__ out = (z == 0) ? q_sum : (z == 1) ? k_sum : v_mean;
    const double alpha = (double)((z == 0) ? aq : (z == 1) ? akp : av)[0];
    const double beta  = (double)((z == 0) ? bq : (z == 1) ? bkp : bv)[0];

    // XCD-chunked bijective swizzle within this z (256 blocks, 256%8==0).
    const int phys = blockIdx.x + 8 * blockIdx.y;
    const int logical = (phys & 7) * 32 + (phys >> 3);
    const int bx = logical & 7, by = logical >> 3;
    const int row0 = by * 128, col0 = bx * 64;

    // limb planes h/m/l; rows of 32 bf16 (64 B), XOR chunk swizzle, no pad.
    __shared__ __align__(16) short As[3][4096];   // 24 KB
    __shared__ __align__(16) short Bs[3][2048];   // 12 KB

    const int tid  = threadIdx.x;
    const int lane = tid & 63, wave = tid >> 6;
    const int qd = lane >> 4, c = lane & 15;
    const int wrow = wave * 32;

    // global_load_lds source offsets (lane-only chunk permutation)
    const int kc8 = ((lane & 3) ^ ((lane >> 3) & 3)) * 8;
    const size_t ga0 = (size_t)(row0 + wave * 16 + (lane >> 2)) * EMB + kc8;       // A q=0
    const size_t ga1 = ga0 + (size_t)64 * EMB;                                     // A q=1
    const size_t gb  = (size_t)(col0 + wave * 16 + (lane >> 2)) * EMB + kc8;       // B

    // frag read offsets (row R, k-chunk qd -> slot qd^((R>>1)&3))
    int arf[2], brf[4];
    #pragma unroll
    for (int i = 0; i < 2; ++i) {
        const int Ra = wrow + i * 16 + c;
        arf[i] = Ra * 32 + ((qd ^ ((Ra >> 1) & 3)) * 8);
    }
    #pragma unroll
    for (int j = 0; j < 4; ++j) {
        const int Rb = j * 16 + c;
        brf[j] = Rb * 32 + ((qd ^ ((Rb >> 1) & 3)) * 8);
    }

    float4v acc[2][4];
    #pragma unroll
    for (int i = 0; i < 2; ++i)
        #pragma unroll
        for (int j = 0; j < 4; ++j)
            acc[i][j] = (float4v){0.f, 0.f, 0.f, 0.f};

    for (int k0 = 0; k0 < EMB; k0 += 32) {
        __syncthreads();   // prior iteration's frag reads complete
        gld16(Xh  + ga0 + k0, &As[0][wave * 512]);
        gld16(Xh  + ga1 + k0, &As[0][2048 + wave * 512]);
        gld16(Xm  + ga0 + k0, &As[1][wave * 512]);
        gld16(Xm  + ga1 + k0, &As[1][2048 + wave * 512]);
        gld16(Xl  + ga0 + k0, &As[2][wave * 512]);
        gld16(Xl  + ga1 + k0, &As[2][2048 + wave * 512]);
        gld16(WTh + gb  + k0, &Bs[0][wave * 512]);
        gld16(WTm + gb  + k0, &Bs[1][wave * 512]);
        gld16(WTl + gb  + k0, &Bs[2][wave * 512]);
        __syncthreads();   // drains vmcnt -> tile visible

        short8 Afh[2], Afm[2], Afl[2];
        #pragma unroll
        for (int i = 0; i < 2; ++i) {
            Afh[i] = *(const short8*)&As[0][arf[i]];
            Afm[i] = *(const short8*)&As[1][arf[i]];
            Afl[i] = *(const short8*)&As[2][arf[i]];
        }
        short8 Bfh[4], Bfm[4], Bfl[4];
        #pragma unroll
        for (int j = 0; j < 4; ++j) {
            Bfh[j] = *(const short8*)&Bs[0][brf[j]];
            Bfm[j] = *(const short8*)&Bs[1][brf[j]];
            Bfl[j] = *(const short8*)&Bs[2][brf[j]];
        }

        #pragma unroll
        for (int i = 0; i < 2; ++i)
            #pragma unroll
            for (int j = 0; j < 4; ++j) {
                float4v t = acc[i][j];
                t = __builtin_amdgcn_mfma_f32_16x16x32_bf16(Afh[i], Bfh[j], t, 0, 0, 0);
                t = __builtin_amdgcn_mfma_f32_16x16x32_bf16(Afh[i], Bfm[j], t, 0, 0, 0);
                t = __builtin_amdgcn_mfma_f32_16x16x32_bf16(Afm[i], Bfh[j], t, 0, 0, 0);
                t = __builtin_amdgcn_mfma_f32_16x16x32_bf16(Afm[i], Bfm[j], t, 0, 0, 0);
                t = __builtin_amdgcn_mfma_f32_16x16x32_bf16(Afh[i], Bfl[j], t, 0, 0, 0);
                t = __builtin_amdgcn_mfma_f32_16x16x32_bf16(Afl[i], Bfh[j], t, 0, 0, 0);
                acc[i][j] = t;
            }
    }

    // ---- LIF epilogue: f64, per-element op order identical to the passing
    // version; 4 cols of a row (same T) run as 4 independent chains.
    #pragma unroll
    for (int i = 0; i < 2; ++i)
        #pragma unroll
        for (int r = 0; r < 4; ++r) {
            const int gm = row0 + wrow + i * 16 + qd * 4 + r;
            const double g0 = scores[gm];
            const double c0 = scores[NROWS + gm];
            const int s = gm & (SEQ - 1);
            const double step = (1.2 - 0.8) / (double)(SEQ - 1);   // np.linspace step
            const double pos  = (double)s * step + 0.8;
            const double score = ((1.0 - 0.3) * g0 + 0.3 * c0) * pos;
            double td = ceil(score * 20.0);
            td = td < 1.0 ? 1.0 : (td > 20.0 ? 20.0 : td);
            const int T = (int)td;
            double cur0 = 0.0, cur1 = 0.0, cur2 = 0.0, cur3 = 0.0;
            double vm0 = 0.0, vm1 = 0.0, vm2 = 0.0, vm3 = 0.0;
            double sp0 = 0.0, sp1 = 0.0, sp2 = 0.0, sp3 = 0.0;
            const double xv0 = (double)acc[i][0][r];
            const double xv1 = (double)acc[i][1][r];
            const double xv2 = (double)acc[i][2][r];
            const double xv3 = (double)acc[i][3][r];
            for (int t = 0; t < T; ++t) {
                cur0 = alpha * cur0 + xv0; vm0 = beta * vm0 + cur0;
                if (vm0 >= 1.0) { sp0 += 1.0; vm0 = 0.0; }
                cur1 = alpha * cur1 + xv1; vm1 = beta * vm1 + cur1;
                if (vm1 >= 1.0) { sp1 += 1.0; vm1 = 0.0; }
                cur2 = alpha * cur2 + xv2; vm2 = beta * vm2 + cur2;
                if (vm2 >= 1.0) { sp2 += 1.0; vm2 = 0.0; }
                cur3 = alpha * cur3 + xv3; vm3 = beta * vm3 + cur3;
                if (vm3 >= 1.0) { sp3 += 1.0; vm3 = 0.0; }
            }
            if (z == 2) { sp0 /= 20.0; sp1 /= 20.0; sp2 /= 20.0; sp3 /= 20.0; }
            const size_t ob = (size_t)gm * EMB + col0 + c;
            out[ob +  0] = f2bf((float)sp0);
            out[ob + 16] = f2bf((float)sp1);
            out[ob + 32] = f2bf((float)sp2);
            out[ob + 48] = f2bf((float)sp3);
        }
}

// ---------------------------------------------------------------------------
// K2: fused flash-style MFMA attention (R10 body, unchanged).
// ---------------------------------------------------------------------------
__global__ __launch_bounds__(256) void attn_mfma_kernel(
    const unsigned short* __restrict__ q, const unsigned short* __restrict__ k,
    const unsigned short* __restrict__ v, unsigned short* __restrict__ attn_bf)
{
    __shared__ __align__(16) short Ks2[2][64 * LDP];
    __shared__ __align__(16) short Vt2[2][64 * LDP];
    __shared__ __align__(16) short Pt[64 * LDP];

    const int b = blockIdx.z, h = blockIdx.y;
    const int i0 = blockIdx.x * 64;
    const int tid  = threadIdx.x;
    const int wave = tid >> 6, lane = tid & 63;
    const int quad = lane >> 4, c = lane & 15;

    const unsigned short* Qb = q + ((size_t)b * SEQ + i0) * EMB + h * 64;
    const unsigned short* Kb = k + (size_t)b * SEQ * EMB + h * 64;
    const unsigned short* Vb = v + (size_t)b * SEQ * EMB + h * 64;

    short8 qf[2];
    {
        const int qrow = wave * 16 + c;
        #pragma unroll
        for (int ks = 0; ks < 2; ++ks) {
            short8 raw = *(const short8*)(Qb + (size_t)qrow * EMB + ks * 32 + quad * 8);
            short8 sc8;
            #pragma unroll
            for (int j = 0; j < 8; ++j)
                sc8[j] = (short)f2bf(bf2f((unsigned short)raw[j]) * 0.125f);
            qf[ks] = sc8;
        }
    }

    // staging thread maps
    const int krow = tid >> 3, kch = tid & 7;
    const int vm_  = tid & 7,  vrp = tid >> 3;
    const int vr   = vrp * 2;
    const int vrch = vr >> 3, vrlow = vr & 7;

    short8 kr0, kr1, vv0, vv1;
    kr0 = *(const short8*)(Kb + (size_t)krow * EMB + kch * 8);
    kr1 = *(const short8*)(Kb + (size_t)(32 + krow) * EMB + kch * 8);
    vv0 = *(const short8*)(Vb + (size_t)vr * EMB + vm_ * 8);
    vv1 = *(const short8*)(Vb + (size_t)(vr + 1) * EMB + vm_ * 8);
    {
        *(short8*)&Ks2[0][krow * LDP + kch * 8] = kr0;
        *(short8*)&Ks2[0][(32 + krow) * LDP + kch * 8] = kr1;
        #pragma unroll
        for (int i = 0; i < 8; ++i) {
            const int d = vm_ * 8 + i;
            const int col = ((vrch ^ vm_) << 3) + vrlow;
            *(int*)&Vt2[0][d * LDP + col] =
                (int)((unsigned)(unsigned short)vv0[i] |
                      ((unsigned)(unsigned short)vv1[i] << 16));
        }
    }

    float m_r[4], l_r[4];
    float4v o[4];
    #pragma unroll
    for (int r = 0; r < 4; ++r) { m_r[r] = -1e30f; l_r[r] = 0.f; }
    #pragma unroll
    for (int nb = 0; nb < 4; ++nb)
        #pragma unroll
        for (int r = 0; r < 4; ++r) o[nb][r] = 0.f;

    for (int jt = 0; jt < SEQ / 64; ++jt) {
        __syncthreads();
        const short* Ks = &Ks2[jt & 1][0];
        const short* Vt = &Vt2[jt & 1][0];

        if (jt + 1 < SEQ / 64) {
            const size_t kb = (size_t)((jt + 1) * 64);
            kr0 = *(const short8*)(Kb + (kb + krow) * EMB + kch * 8);
            kr1 = *(const short8*)(Kb + (kb + 32 + krow) * EMB + kch * 8);
            vv0 = *(const short8*)(Vb + (kb + vr) * EMB + vm_ * 8);
            vv1 = *(const short8*)(Vb + (kb + vr + 1) * EMB + vm_ * 8);
        }

        float sc[4][4];
        #pragma unroll
        for (int nb = 0; nb < 4; ++nb) {
            float4v acc = {0.f, 0.f, 0.f, 0.f};
            #pragma unroll
            for (int ks = 0; ks < 2; ++ks) {
                short8 bfrag = *(const short8*)&Ks[(nb * 16 + c) * LDP + ks * 32 + quad * 8];
                acc = __builtin_amdgcn_mfma_f32_16x16x32_bf16(qf[ks], bfrag, acc, 0, 0, 0);
            }
            #pragma unroll
            for (int r = 0; r < 4; ++r) sc[nb][r] = acc[r];
        }

        float mnew[4], alpha[4];
        #pragma unroll
        for (int r = 0; r < 4; ++r) {
            float mx = fmaxf(fmaxf(sc[0][r], sc[1][r]), fmaxf(sc[2][r], sc[3][r]));
            #pragma unroll
            for (int off = 8; off >= 1; off >>= 1) mx = fmaxf(mx, __shfl_xor(mx, off));
            mnew[r]  = fmaxf(m_r[r], mx);
            alpha[r] = __expf(m_r[r] - mnew[r]);
            m_r[r]   = mnew[r];
        }
        float psum[4] = {0.f, 0.f, 0.f, 0.f};
        #pragma unroll
        for (int nb = 0; nb < 4; ++nb)
            #pragma unroll
            for (int r = 0; r < 4; ++r) {
                float p = __expf(sc[nb][r] - mnew[r]);
                psum[r] += p;
                Pt[(wave * 16 + quad * 4 + r) * LDP + nb * 16 + c] = (short)f2bf(p);
            }
        #pragma unroll
        for (int r = 0; r < 4; ++r) {
            float s = psum[r];
            #pragma unroll
            for (int off = 8; off >= 1; off >>= 1) s += __shfl_xor(s, off);
            l_r[r] = l_r[r] * alpha[r] + s;
            #pragma unroll
            for (int nb = 0; nb < 4; ++nb) o[nb][r] *= alpha[r];
        }

        short8 pf[2];
        #pragma unroll
        for (int ks = 0; ks < 2; ++ks)
            pf[ks] = *(const short8*)&Pt[(wave * 16 + c) * LDP + ks * 32 + quad * 8];
        #pragma unroll
        for (int nb = 0; nb < 4; ++nb) {
            float4v acc = o[nb];
            #pragma unroll
            for (int ks = 0; ks < 2; ++ks) {
                const int d = nb * 16 + c;
                const int kch2 = ks * 4 + quad;
                const int col = ((kch2 ^ (d >> 3)) << 3);
                short8 vfrag = *(const short8*)&Vt[d * LDP + col];
                acc = __builtin_amdgcn_mfma_f32_16x16x32_bf16(pf[ks], vfrag, acc, 0, 0, 0);
            }
            o[nb] = acc;
        }

        if (jt + 1 < SEQ / 64) {
            const int nb2 = (jt + 1) & 1;
            *(short8*)&Ks2[nb2][krow * LDP + kch * 8] = kr0;
            *(short8*)&Ks2[nb2][(32 + krow) * LDP + kch * 8] = kr1;
            #pragma unroll
            for (int i = 0; i < 8; ++i) {
                const int d = vm_ * 8 + i;
                const int col = ((vrch ^ vm_) << 3) + vrlow;
                *(int*)&Vt2[nb2][d * LDP + col] =
                    (int)((unsigned)(unsigned short)vv0[i] |
                          ((unsigned)(unsigned short)vv1[i] << 16));
            }
        }
    }

    #pragma unroll
    for (int r = 0; r < 4; ++r) {
        const float inv = 1.0f / l_r[r];
        const int row = i0 + wave * 16 + quad * 4 + r;
        #pragma unroll
        for (int nb = 0; nb < 4; ++nb)
            attn_bf[((size_t)b * SEQ + row) * EMB + h * 64 + nb * 16 + c] =
                f2bf(o[nb][r] * inv);
    }
}

// ---------------------------------------------------------------------------
// K3: out partials. R11: split-K x2 (blockIdx.z = K-half) -> 1024 blocks,
// 4 blocks/CU, 16 waves/CU (TLP was the binding constraint; R10's intra-block
// dbuf was neutral). z=0 writes its partial to d_out, z=1 to p1; combine adds
// them + bias. Reassociation (S0+S1)+bias vs serial ~1e-6 abs << absmax.
// ---------------------------------------------------------------------------
__global__ __launch_bounds__(256) void out_gemm_kernel(
    const unsigned short* __restrict__ A,   // [4096][512] bf16
    const unsigned short* __restrict__ BT,  // [512][512] bf16, [n][k]
    float* __restrict__ out, float* __restrict__ p1)
{
    __shared__ __align__(16) short As2[2][4096], Bs2[2][4096];   // 32 KB

    const int tid  = threadIdx.x;
    const int lane = tid & 63, wave = tid >> 6;
    const int qd = lane >> 4, c = lane & 15;
    const int zk = blockIdx.z;               // K-half
    const int kbase = zk * 256;

    // XCD-chunked bijective swizzle (512 blocks per z, 512%8==0).
    const int phys = blockIdx.x + 8 * blockIdx.y;
    const int logical = (phys & 7) * 64 + (phys >> 3);
    const int bx = logical & 7, by = logical >> 3;
    const int row0 = by * 64, col0 = bx * 64;

    // staging map: thread -> row sr, chunk pair {sj, sj+1} (32B contiguous)
    const int sr = tid >> 2, sj = (tid & 3) * 2;
    const size_t gA = (size_t)(row0 + sr) * EMB + sj * 8 + kbase;
    const size_t gB = (size_t)(col0 + sr) * EMB + sj * 8 + kbase;
    const int dA0 = sr * 64 + ((sj ^ (sr & 7)) * 8);
    const int dA1 = sr * 64 + (((sj + 1) ^ (sr & 7)) * 8);

    // frag read offsets: row R, logical chunk kk*4+qd -> slot ^(c&7)
    int arf[2], brf[4][2];
    #pragma unroll
    for (int kk = 0; kk < 2; ++kk) {
        arf[kk] = (wave * 16 + c) * 64 + (((kk * 4 + qd) ^ (c & 7)) * 8);
        #pragma unroll
        for (int j = 0; j < 4; ++j)
            brf[j][kk] = (j * 16 + c) * 64 + (((kk * 4 + qd) ^ (c & 7)) * 8);
    }

    float4v acc[4];
    #pragma unroll
    for (int j = 0; j < 4; ++j) acc[j] = (float4v){0.f, 0.f, 0.f, 0.f};

    short8 ra0, ra1, rb0, rb1;
    ra0 = *(const short8*)&A[gA];      ra1 = *(const short8*)&A[gA + 8];
    rb0 = *(const short8*)&BT[gB];     rb1 = *(const short8*)&BT[gB + 8];
    *(short8*)&As2[0][dA0] = ra0; *(short8*)&As2[0][dA1] = ra1;
    *(short8*)&Bs2[0][dA0] = rb0; *(short8*)&Bs2[0][dA1] = rb1;

    for (int it = 0; it < 4; ++it) {
        __syncthreads();
        const int cur = it & 1;
        if (it < 3) {
            const int k0 = (it + 1) * 64;
            ra0 = *(const short8*)&A[gA + k0];  ra1 = *(const short8*)&A[gA + k0 + 8];
            rb0 = *(const short8*)&BT[gB + k0]; rb1 = *(const short8*)&BT[gB + k0 + 8];
        }
        #pragma unroll
        for (int kk = 0; kk < 2; ++kk) {
            const short8 af = *(const short8*)&As2[cur][arf[kk]];
            #pragma unroll
            for (int j = 0; j < 4; ++j) {
                const short8 bf = *(const short8*)&Bs2[cur][brf[j][kk]];
                acc[j] = __builtin_amdgcn_mfma_f32_16x16x32_bf16(af, bf, acc[j], 0, 0, 0);
            }
        }
        if (it < 3) {
            const int nxt = cur ^ 1;
            *(short8*)&As2[nxt][dA0] = ra0; *(short8*)&As2[nxt][dA1] = ra1;
            *(short8*)&Bs2[nxt][dA0] = rb0; *(short8*)&Bs2[nxt][dA1] = rb1;
        }
    }

    float* __restrict__ dst = (zk == 0) ? out : p1;
    #pragma unroll
    for (int j = 0; j < 4; ++j)
        #pragma unroll
        for (int r = 0; r < 4; ++r) {
            const int gm = row0 + wave * 16 + qd * 4 + r;
            const int gn = col0 + j * 16 + c;
            dst[(size_t)gm * EMB + gn] = acc[j][r];
        }
}

// ---------------------------------------------------------------------------
// K4: out combine: out = p0(out) + p1 + bias. float4, 2048 blocks.
// ---------------------------------------------------------------------------
__global__ __launch_bounds__(256) void out_combine_kernel(
    float* __restrict__ out, const float* __restrict__ p1,
    const float* __restrict__ bias)
{
    const size_t i0 = ((size_t)blockIdx.x * 256 + threadIdx.x) * 4;
    float4 a = *(const float4*)&out[i0];
    const float4 b = *(const float4*)&p1[i0];
    const int col = (int)(i0 & (EMB - 1));
    const float4 bb = *(const float4*)&bias[col];
    a.x += b.x + bb.x; a.y += b.y + bb.y;
    a.z += b.z + bb.z; a.w += b.w + bb.w;
    *(float4*)&out[i0] = a;
}

// ---------------------------------------------------------------------------
extern "C" void kernel_launch(void* const* d_in, const int* in_sizes, int n_in,
                              void* d_out, int out_size, void* d_ws, size_t ws_size,
                              hipStream_t stream)
{
    const float* x   = (const float*)d_in[0];
    const float* Wq  = (const float*)d_in[1];
    const float* Wk  = (const float*)d_in[2];
    const float* Wv  = (const float*)d_in[3];
    const float* Wo  = (const float*)d_in[4];
    const float* bo  = (const float*)d_in[5];
    const float* gW1 = (const float*)d_in[6];
    const float* gb1 = (const float*)d_in[7];
    const float* gg  = (const float*)d_in[8];
    const float* gbe = (const float*)d_in[9];
    const float* gW2 = (const float*)d_in[10];
    const float* gb2 = (const float*)d_in[11];
    const float* gW3 = (const float*)d_in[12];
    const float* gb3 = (const float*)d_in[13];
    const float* cW1 = (const float*)d_in[14];
    const float* cb1 = (const float*)d_in[15];
    const float* cg  = (const float*)d_in[16];
    const float* cbe = (const float*)d_in[17];
    const float* cW2 = (const float*)d_in[18];
    const float* cb2 = (const float*)d_in[19];
    const float* cW3 = (const float*)d_in[20];
    const float* cb3 = (const float*)d_in[21];
    const float* aq  = (const float*)d_in[22];
    const float* bq  = (const float*)d_in[23];
    const float* ak  = (const float*)d_in[24];
    const float* bk  = (const float*)d_in[25];
    const float* av  = (const float*)d_in[26];
    const float* bv  = (const float*)d_in[27];

    unsigned short* q_sum   = (unsigned short*)((char*)d_ws + 16384);
    unsigned short* k_sum   = q_sum   + (size_t)NROWS * EMB;
    unsigned short* v_mean  = k_sum   + (size_t)NROWS * EMB;
    unsigned short* attn_bf = v_mean  + (size_t)NROWS * EMB;
    unsigned short* WoT     = attn_bf + (size_t)NROWS * EMB;
    unsigned short* WL      = WoT     + (size_t)EMB * EMB;     // 3z x 3limb x [512][512] bf16
    unsigned short* XLp     = WL      + (size_t)9 * EMB * EMB; // 3limb x [4096][512] bf16
    double* scores          = (double*)(XLp + (size_t)3 * NROWS * EMB); // [2][4096] f64
    float* p1               = (float*)(scores + 2 * NROWS);    // [4096][512] f32, 8 MB
    float* out = (float*)d_out;

    pre_kernel<<<dim3(3328), dim3(256), 0, stream>>>(
        x, gW1, gb1, gg, gbe, gW2, gb2, gW3, gb3,
        cW1, cb1, cg, cbe, cW2, cb2, cW3, cb3, scores,
        Wq, Wk, Wv, WL, XLp, Wo, WoT);

    qkv_mfma_lif_kernel<<<dim3(EMB / 64, NROWS / 128, 3), dim3(256), 0, stream>>>(
        XLp, WL, aq, bq, ak, bk, av, bv, scores, q_sum, k_sum, v_mean);

    attn_mfma_kernel<<<dim3(SEQ / 64, 8, 4), dim3(256), 0, stream>>>(
        q_sum, k_sum, v_mean, attn_bf);

    out_gemm_kernel<<<dim3(EMB / 64, NROWS / 64, 2), dim3(256), 0, stream>>>(
        attn_bf, WoT, out, p1);

    out_combine_kernel<<<dim3(NROWS * EMB / (256 * 4)), dim3(256), 0, stream>>>(
        out, p1, bo);
}

// Round 12
// 253.420 us; speedup vs baseline: 1.0486x; 1.0486x over previous
//
#include <hip/hip_runtime.h>
#include <math.h>

// Problem constants (B=4, S=1024, E=512, H=8, D=64, T_MAX=20)
#define SEQ   1024
#define EMB   512
#define NROWS 4096   // B*S
#define LDP   72     // attn LDS row stride (bf16 elems)
#define GROWS 4      // gates rows per block

typedef __attribute__((ext_vector_type(8))) short short8;    // bf16 x8 MFMA frag
typedef __attribute__((ext_vector_type(4))) float float4v;   // f32 x4 MFMA acc

__device__ __forceinline__ float bf2f(unsigned short s) {
    union { float f; unsigned u; } x; x.u = ((unsigned)s) << 16; return x.f;
}
__device__ __forceinline__ unsigned short f2bf(float f) {
    union { float f; unsigned u; } x; x.f = f;
    unsigned r = x.u + 0x7fffu + ((x.u >> 16) & 1u);   // round-to-nearest-even
    return (unsigned short)(r >> 16);
}

// async global->LDS 16B: LDS dest = wave-uniform base + lane*16 (HW rule).
__device__ __forceinline__ void gld16(const unsigned short* g, short* l) {
    __builtin_amdgcn_global_load_lds(
        (__attribute__((address_space(1))) void*)(g),
        (__attribute__((address_space(3))) void*)(l), 16, 0, 0);
}

// 3-limb bf16 split: x ~= h + m + l. Residual subtractions are Sterbenz-exact,
// so h+m+l carries ~26 mantissa bits of x; per-limb repr error <= 2^-27 |x|.
__device__ __forceinline__ void split3(float x, unsigned short& h, unsigned short& m, unsigned short& l) {
    union { float f; unsigned u; } a; a.f = x;
    const unsigned rh = a.u + 0x7fffu + ((a.u >> 16) & 1u);
    h = (unsigned short)(rh >> 16);
    union { float f; unsigned u; } hf; hf.u = rh & 0xffff0000u;
    const float r1 = x - hf.f;                 // exact
    a.f = r1;
    const unsigned rm = a.u + 0x7fffu + ((a.u >> 16) & 1u);
    m = (unsigned short)(rm >> 16);
    union { float f; unsigned u; } mf; mf.u = rm & 0xffff0000u;
    const float r2 = r1 - mf.f;                // exact
    l = f2bf(r2);
}

// ---------------------------------------------------------------------------
// gate/complexity MLP evaluator (R6/R10 form: xs in f64 -- R11's f32-xs added
// a v_cvt per FMA and regressed; reverted). Bit-identical to R4/R6/R10.
// ---------------------------------------------------------------------------
template<int H1, int H2>
__device__ __forceinline__ double mlp_eval(
    const double xs[GROWS][EMB], double* h1, double* h2, double* red,
    double* mu_s, double* var_s,
    const float* __restrict__ W1, const float* __restrict__ b1,
    const float* __restrict__ gam, const float* __restrict__ bet,
    const float* __restrict__ W2, const float* __restrict__ b2,
    const float* __restrict__ W3, const float* __restrict__ b3,
    int tid, int myrow)
{
    constexpr int S  = 256 / H1;    // k-slices: 2 (gate), 4 (complexity)
    constexpr int KS = EMB / S;     // 256 or 128

    {   // h1 partials: thread = (col, k-slice), 4-row ILP
        const int col = tid % H1, sk = tid / H1;
        double acc[GROWS] = {0.0, 0.0, 0.0, 0.0};
        const int kbeg = sk * KS;
        #pragma unroll 4
        for (int k = kbeg; k < kbeg + KS; ++k) {
            const double w = (double)W1[k * H1 + col];
            #pragma unroll
            for (int r = 0; r < GROWS; ++r) acc[r] += w * xs[r][k];
        }
        #pragma unroll
        for (int r = 0; r < GROWS; ++r) red[(sk * GROWS + r) * H1 + col] = acc[r];
    }
    __syncthreads();
    for (int idx = tid; idx < GROWS * H1; idx += 256) {   // reduce + bias
        const int r = idx / H1, cc = idx % H1;
        double s = 0.0;
        #pragma unroll
        for (int t = 0; t < S; ++t) s += red[(t * GROWS + r) * H1 + cc];
        h1[r * H1 + cc] = s + (double)b1[cc];
    }
    __syncthreads();

    {   // mean: wave w owns row w
        const int w = tid >> 6, l = tid & 63;
        double s = 0.0;
        for (int c = l; c < H1; c += 64) s += h1[w * H1 + c];
        #pragma unroll
        for (int off = 32; off >= 1; off >>= 1) s += __shfl_xor(s, off);
        if (l == 0) mu_s[w] = s / (double)H1;
    }
    __syncthreads();
    {   // var
        const int w = tid >> 6, l = tid & 63;
        const double mu = mu_s[w];
        double s = 0.0;
        for (int c = l; c < H1; c += 64) { const double d = h1[w * H1 + c] - mu; s += d * d; }
        #pragma unroll
        for (int off = 32; off >= 1; off >>= 1) s += __shfl_xor(s, off);
        if (l == 0) var_s[w] = s / (double)H1;
    }
    __syncthreads();
    // normalize + relu
    for (int idx = tid; idx < GROWS * H1; idx += 256) {
        const int r = idx / H1, cc = idx % H1;
        double hn = (h1[r * H1 + cc] - mu_s[r]) / sqrt(var_s[r] + 1e-5) * (double)gam[cc] + (double)bet[cc];
        h1[r * H1 + cc] = hn > 0.0 ? hn : 0.0;
    }
    __syncthreads();

    {   // h2 = relu(h1 @ W2 + b2)
        const int col = tid % H2;
        const int r   = tid / H2;
        if (r < GROWS) {
            double acc = (double)b2[col];
            for (int k = 0; k < H1; ++k)
                acc += (double)W2[k * H2 + col] * h1[r * H1 + k];
            h2[r * H2 + col] = acc > 0.0 ? acc : 0.0;
        }
    }
    __syncthreads();

    {   // scalar = h2 @ W3: wave w owns row w
        const int w = tid >> 6, l = tid & 63;
        double s = 0.0;
        for (int c = l; c < H2; c += 64) s += h2[w * H2 + c] * (double)W3[c];
        #pragma unroll
        for (int off = 32; off >= 1; off >>= 1) s += __shfl_xor(s, off);
        if (l == 0) mu_s[w] = s;   // reuse as scratch
    }
    __syncthreads();
    double ret = 0.0;
    if (myrow >= 0) {
        const double z = mu_s[myrow] + (double)b3[0];
        ret = 1.0 / (1.0 + exp(-z));
    }
    return ret;
}

// ---------------------------------------------------------------------------
// K0: fused pre-kernel (R10 body, reverted): gates / x_limbs / w_limbs / wot.
// ---------------------------------------------------------------------------
__global__ __launch_bounds__(256) void pre_kernel(
    const float* __restrict__ x,
    const float* __restrict__ gW1, const float* __restrict__ gb1,
    const float* __restrict__ gg,  const float* __restrict__ gbe,
    const float* __restrict__ gW2, const float* __restrict__ gb2,
    const float* __restrict__ gW3, const float* __restrict__ gb3,
    const float* __restrict__ cW1, const float* __restrict__ cb1,
    const float* __restrict__ cg,  const float* __restrict__ cbe,
    const float* __restrict__ cW2, const float* __restrict__ cb2,
    const float* __restrict__ cW3, const float* __restrict__ cb3,
    double* __restrict__ scores,
    const float* __restrict__ Wq, const float* __restrict__ Wk,
    const float* __restrict__ Wv, unsigned short* __restrict__ WL,
    unsigned short* __restrict__ XL,
    const float* __restrict__ Wo, unsigned short* __restrict__ WoT)
{
    __shared__ __align__(16) char smem[30784];
    const int bid = blockIdx.x;
    const int tid = threadIdx.x;

    if (bid < 2048) {
        // ---- gates ----
        double (*xs)[EMB] = (double(*)[EMB])smem;            // 16384 B
        double* h1    = (double*)(smem + 16384);             // 4096 B
        double* h2    = (double*)(smem + 20480);             // 2048 B
        double* red   = (double*)(smem + 22528);             // 8192 B
        double* mu_s  = (double*)(smem + 30720);
        double* var_s = (double*)(smem + 30752);

        const int gx = bid & 1023, gy = bid >> 10;
        const int row0 = gx * GROWS;

        for (int idx = tid; idx < GROWS * EMB; idx += 256) {
            const int r = idx >> 9, cc = idx & 511;
            xs[r][cc] = (double)x[(size_t)(row0 + r) * EMB + cc];
        }
        __syncthreads();

        const int myrow = (tid < GROWS) ? tid : -1;
        double v;
        if (gy == 0)
            v = mlp_eval<128, 64>(xs, h1, h2, red, mu_s, var_s,
                                  gW1, gb1, gg, gbe, gW2, gb2, gW3, gb3, tid, myrow);
        else
            v = mlp_eval<64, 32>(xs, h1, h2, red, mu_s, var_s,
                                 cW1, cb1, cg, cbe, cW2, cb2, cW3, cb3, tid, myrow);

        if (myrow >= 0)
            scores[(size_t)gy * NROWS + row0 + myrow] = v;

    } else if (bid < 3072) {
        // ---- x limb prep ----
        unsigned short* Xh = XL;
        unsigned short* Xm = XL + (size_t)NROWS * EMB;
        unsigned short* Xl = Xm + (size_t)NROWS * EMB;
        const size_t i0 = ((size_t)(bid - 2048) * 256 + tid) * 8;
        const float4 a0 = *(const float4*)&x[i0];
        const float4 a1 = *(const float4*)&x[i0 + 4];
        const float av8[8] = {a0.x, a0.y, a0.z, a0.w, a1.x, a1.y, a1.z, a1.w};
        short8 ph, pm, pl;
        #pragma unroll
        for (int e = 0; e < 8; ++e) {
            unsigned short h, m, l;
            split3(av8[e], h, m, l);
            ph[e] = (short)h; pm[e] = (short)m; pl[e] = (short)l;
        }
        *(short8*)&Xh[i0] = ph;
        *(short8*)&Xm[i0] = pm;
        *(short8*)&Xl[i0] = pl;

    } else if (bid < 3264) {
        // ---- W^T limb prep ----
        const int t = bid - 3072;
        const int z = t >> 6, rem = t & 63;
        const int k0 = (rem >> 3) * 64, n0 = (rem & 7) * 64;
        const float* __restrict__ W = (z == 0) ? Wq : (z == 1) ? Wk : Wv;
        unsigned short* Th = WL + (size_t)z * 3 * EMB * EMB;
        unsigned short* Tm = Th + (size_t)EMB * EMB;
        unsigned short* Tl = Tm + (size_t)EMB * EMB;

        float (*Ws)[68] = (float(*)[68])smem;   // 17408 B
        #pragma unroll
        for (int it = 0; it < 4; ++it) {
            const int idx = it * 256 + tid;
            const int r = idx >> 4, c4 = (idx & 15) * 4;
            *(float4*)&Ws[r][c4] = *(const float4*)&W[(size_t)(k0 + r) * EMB + n0 + c4];
        }
        __syncthreads();
        #pragma unroll
        for (int it = 0; it < 2; ++it) {
            const int idx = it * 256 + tid;
            const int n = idx >> 3, k8 = (idx & 7) * 8;
            short8 ph, pm, pl;
            #pragma unroll
            for (int j = 0; j < 8; ++j) {
                unsigned short h, m, l;
                split3(Ws[k8 + j][n], h, m, l);
                ph[j] = (short)h; pm[j] = (short)m; pl[j] = (short)l;
            }
            const size_t o = (size_t)(n0 + n) * EMB + k0 + k8;
            *(short8*)&Th[o] = ph;
            *(short8*)&Tm[o] = pm;
            *(short8*)&Tl[o] = pl;
        }

    } else {
        // ---- Wo^T bf16 prep ----
        const int t = bid - 3264;
        const int k0 = (t >> 3) * 64, n0 = (t & 7) * 64;
        unsigned short (*Ws)[72] = (unsigned short(*)[72])smem;   // 9216 B
        #pragma unroll
        for (int it = 0; it < 4; ++it) {
            const int idx = it * 256 + tid;
            const int r = idx >> 4, c4 = (idx & 15) * 4;
            const float4 w4 = *(const float4*)&Wo[(size_t)(k0 + r) * EMB + n0 + c4];
            Ws[r][c4 + 0] = f2bf(w4.x); Ws[r][c4 + 1] = f2bf(w4.y);
            Ws[r][c4 + 2] = f2bf(w4.z); Ws[r][c4 + 3] = f2bf(w4.w);
        }
        __syncthreads();
        #pragma unroll
        for (int it = 0; it < 2; ++it) {
            const int idx = it * 256 + tid;
            const int n = idx >> 3, k8 = (idx & 7) * 8;
            short8 pack;
            #pragma unroll
            for (int j = 0; j < 8; ++j) pack[j] = (short)Ws[k8 + j][n];
            *(short8*)&WoT[(size_t)(n0 + n) * EMB + k0 + k8] = pack;
        }
    }
}

// ---------------------------------------------------------------------------
// K1: QKV GEMM, 3-limb split-bf16 MFMA (R6/R9 body, unchanged).
// ---------------------------------------------------------------------------
__global__ __launch_bounds__(256) void qkv_mfma_lif_kernel(
    const unsigned short* __restrict__ XL, const unsigned short* __restrict__ WL,
    const float* __restrict__ aq, const float* __restrict__ bq,
    const float* __restrict__ akp, const float* __restrict__ bkp,
    const float* __restrict__ av, const float* __restrict__ bv,
    const double* __restrict__ scores,
    unsigned short* __restrict__ q_sum, unsigned short* __restrict__ k_sum,
    unsigned short* __restrict__ v_mean)
{
    const int z = blockIdx.z;
    const unsigned short* __restrict__ WTh = WL + (size_t)z * 3 * EMB * EMB;
    const unsigned short* __restrict__ WTm = WTh + (size_t)EMB * EMB;
    const unsigned short* __restrict__ WTl = WTm + (size_t)EMB * EMB;
    const unsigned short* __restrict__ Xh = XL;
    const unsigned short* __restrict__ Xm = XL + (size_t)NROWS * EMB;
    const unsigned short* __restrict__ Xl = Xm + (size_t)NROWS * EMB;
    unsigned short* __restrict__ out = (z == 0) ? q_sum : (z == 1) ? k_sum : v_mean;
    const double alpha = (double)((z == 0) ? aq : (z == 1) ? akp : av)[0];
    const double beta  = (double)((z == 0) ? bq : (z == 1) ? bkp : bv)[0];

    // XCD-chunked bijective swizzle within this z (256 blocks, 256%8==0).
    const int phys = blockIdx.x + 8 * blockIdx.y;
    const int logical = (phys & 7) * 32 + (phys >> 3);
    const int bx = logical & 7, by = logical >> 3;
    const int row0 = by * 128, col0 = bx * 64;

    // limb planes h/m/l; rows of 32 bf16 (64 B), XOR chunk swizzle, no pad.
    __shared__ __align__(16) short As[3][4096];   // 24 KB
    __shared__ __align__(16) short Bs[3][2048];   // 12 KB

    const int tid  = threadIdx.x;
    const int lane = tid & 63, wave = tid >> 6;
    const int qd = lane >> 4, c = lane & 15;
    const int wrow = wave * 32;

    // global_load_lds source offsets (lane-only chunk permutation)
    const int kc8 = ((lane & 3) ^ ((lane >> 3) & 3)) * 8;
    const size_t ga0 = (size_t)(row0 + wave * 16 + (lane >> 2)) * EMB + kc8;       // A q=0
    const size_t ga1 = ga0 + (size_t)64 * EMB;                                     // A q=1
    const size_t gb  = (size_t)(col0 + wave * 16 + (lane >> 2)) * EMB + kc8;       // B

    // frag read offsets (row R, k-chunk qd -> slot qd^((R>>1)&3))
    int arf[2], brf[4];
    #pragma unroll
    for (int i = 0; i < 2; ++i) {
        const int Ra = wrow + i * 16 + c;
        arf[i] = Ra * 32 + ((qd ^ ((Ra >> 1) & 3)) * 8);
    }
    #pragma unroll
    for (int j = 0; j < 4; ++j) {
        const int Rb = j * 16 + c;
        brf[j] = Rb * 32 + ((qd ^ ((Rb >> 1) & 3)) * 8);
    }

    float4v acc[2][4];
    #pragma unroll
    for (int i = 0; i < 2; ++i)
        #pragma unroll
        for (int j = 0; j < 4; ++j)
            acc[i][j] = (float4v){0.f, 0.f, 0.f, 0.f};

    for (int k0 = 0; k0 < EMB; k0 += 32) {
        __syncthreads();   // prior iteration's frag reads complete
        gld16(Xh  + ga0 + k0, &As[0][wave * 512]);
        gld16(Xh  + ga1 + k0, &As[0][2048 + wave * 512]);
        gld16(Xm  + ga0 + k0, &As[1][wave * 512]);
        gld16(Xm  + ga1 + k0, &As[1][2048 + wave * 512]);
        gld16(Xl  + ga0 + k0, &As[2][wave * 512]);
        gld16(Xl  + ga1 + k0, &As[2][2048 + wave * 512]);
        gld16(WTh + gb  + k0, &Bs[0][wave * 512]);
        gld16(WTm + gb  + k0, &Bs[1][wave * 512]);
        gld16(WTl + gb  + k0, &Bs[2][wave * 512]);
        __syncthreads();   // drains vmcnt -> tile visible

        short8 Afh[2], Afm[2], Afl[2];
        #pragma unroll
        for (int i = 0; i < 2; ++i) {
            Afh[i] = *(const short8*)&As[0][arf[i]];
            Afm[i] = *(const short8*)&As[1][arf[i]];
            Afl[i] = *(const short8*)&As[2][arf[i]];
        }
        short8 Bfh[4], Bfm[4], Bfl[4];
        #pragma unroll
        for (int j = 0; j < 4; ++j) {
            Bfh[j] = *(const short8*)&Bs[0][brf[j]];
            Bfm[j] = *(const short8*)&Bs[1][brf[j]];
            Bfl[j] = *(const short8*)&Bs[2][brf[j]];
        }

        #pragma unroll
        for (int i = 0; i < 2; ++i)
            #pragma unroll
            for (int j = 0; j < 4; ++j) {
                float4v t = acc[i][j];
                t = __builtin_amdgcn_mfma_f32_16x16x32_bf16(Afh[i], Bfh[j], t, 0, 0, 0);
                t = __builtin_amdgcn_mfma_f32_16x16x32_bf16(Afh[i], Bfm[j], t, 0, 0, 0);
                t = __builtin_amdgcn_mfma_f32_16x16x32_bf16(Afm[i], Bfh[j], t, 0, 0, 0);
                t = __builtin_amdgcn_mfma_f32_16x16x32_bf16(Afm[i], Bfm[j], t, 0, 0, 0);
                t = __builtin_amdgcn_mfma_f32_16x16x32_bf16(Afh[i], Bfl[j], t, 0, 0, 0);
                t = __builtin_amdgcn_mfma_f32_16x16x32_bf16(Afl[i], Bfh[j], t, 0, 0, 0);
                acc[i][j] = t;
            }
    }

    // ---- LIF epilogue: f64, per-element op order identical to the passing
    // version; 4 cols of a row (same T) run as 4 independent chains.
    #pragma unroll
    for (int i = 0; i < 2; ++i)
        #pragma unroll
        for (int r = 0; r < 4; ++r) {
            const int gm = row0 + wrow + i * 16 + qd * 4 + r;
            const double g0 = scores[gm];
            const double c0 = scores[NROWS + gm];
            const int s = gm & (SEQ - 1);
            const double step = (1.2 - 0.8) / (double)(SEQ - 1);   // np.linspace step
            const double pos  = (double)s * step + 0.8;
            const double score = ((1.0 - 0.3) * g0 + 0.3 * c0) * pos;
            double td = ceil(score * 20.0);
            td = td < 1.0 ? 1.0 : (td > 20.0 ? 20.0 : td);
            const int T = (int)td;
            double cur0 = 0.0, cur1 = 0.0, cur2 = 0.0, cur3 = 0.0;
            double vm0 = 0.0, vm1 = 0.0, vm2 = 0.0, vm3 = 0.0;
            double sp0 = 0.0, sp1 = 0.0, sp2 = 0.0, sp3 = 0.0;
            const double xv0 = (double)acc[i][0][r];
            const double xv1 = (double)acc[i][1][r];
            const double xv2 = (double)acc[i][2][r];
            const double xv3 = (double)acc[i][3][r];
            for (int t = 0; t < T; ++t) {
                cur0 = alpha * cur0 + xv0; vm0 = beta * vm0 + cur0;
                if (vm0 >= 1.0) { sp0 += 1.0; vm0 = 0.0; }
                cur1 = alpha * cur1 + xv1; vm1 = beta * vm1 + cur1;
                if (vm1 >= 1.0) { sp1 += 1.0; vm1 = 0.0; }
                cur2 = alpha * cur2 + xv2; vm2 = beta * vm2 + cur2;
                if (vm2 >= 1.0) { sp2 += 1.0; vm2 = 0.0; }
                cur3 = alpha * cur3 + xv3; vm3 = beta * vm3 + cur3;
                if (vm3 >= 1.0) { sp3 += 1.0; vm3 = 0.0; }
            }
            if (z == 2) { sp0 /= 20.0; sp1 /= 20.0; sp2 /= 20.0; sp3 /= 20.0; }
            const size_t ob = (size_t)gm * EMB + col0 + c;
            out[ob +  0] = f2bf((float)sp0);
            out[ob + 16] = f2bf((float)sp1);
            out[ob + 32] = f2bf((float)sp2);
            out[ob + 48] = f2bf((float)sp3);
        }
}

// ---------------------------------------------------------------------------
// K2: flash attention with KV-SPLIT x2 (flash-decoding style). Each block
// processes 8 of the 16 KV tiles (blockIdx.z = b*2... packed as z = kv*4+b),
// single-buffered R9 body (27.6 KB LDS -> grid 1024 = 4 blocks/CU, 2x TLP,
// half the serial chain). Partials (m, l, o) per row go to workspace; the
// combine kernel merges the two halves (softmax reassociation ~1e-7 rel;
// attn_bf at most rare 1-ulp flips -> out perturbation ~1e-4 << absmax).
// ---------------------------------------------------------------------------
__global__ __launch_bounds__(256) void attn_mfma_kernel(
    const unsigned short* __restrict__ q, const unsigned short* __restrict__ k,
    const unsigned short* __restrict__ v,
    float* __restrict__ OP, float* __restrict__ MP, float* __restrict__ LP)
{
    __shared__ __align__(16) short Ks[64 * LDP];
    __shared__ __align__(16) short Pt[64 * LDP];
    __shared__ __align__(16) short Vt[64 * LDP];

    const int b = blockIdx.z & 3, kv = blockIdx.z >> 2;
    const int h = blockIdx.y;
    const int i0 = blockIdx.x * 64;
    const int tid  = threadIdx.x;
    const int wave = tid >> 6, lane = tid & 63;
    const int quad = lane >> 4, c = lane & 15;

    const unsigned short* Qb = q + ((size_t)b * SEQ + i0) * EMB + h * 64;
    const unsigned short* Kb = k + (size_t)b * SEQ * EMB + h * 64;
    const unsigned short* Vb = v + (size_t)b * SEQ * EMB + h * 64;

    short8 qf[2];
    {
        const int qrow = wave * 16 + c;
        #pragma unroll
        for (int ks = 0; ks < 2; ++ks) {
            short8 raw = *(const short8*)(Qb + (size_t)qrow * EMB + ks * 32 + quad * 8);
            short8 sc8;
            #pragma unroll
            for (int j = 0; j < 8; ++j)
                sc8[j] = (short)f2bf(bf2f((unsigned short)raw[j]) * 0.125f);
            qf[ks] = sc8;
        }
    }

    float m_r[4], l_r[4];
    float4v o[4];
    #pragma unroll
    for (int r = 0; r < 4; ++r) { m_r[r] = -1e30f; l_r[r] = 0.f; }
    #pragma unroll
    for (int nb = 0; nb < 4; ++nb)
        #pragma unroll
        for (int r = 0; r < 4; ++r) o[nb][r] = 0.f;

    for (int jt = kv * 8; jt < kv * 8 + 8; ++jt) {
        #pragma unroll
        for (int it = 0; it < 2; ++it) {
            const int idx = it * 256 + tid;
            const int row = idx >> 3, ch = idx & 7;
            short8 val = *(const short8*)(Kb + (size_t)(jt * 64 + row) * EMB + ch * 8);
            *(short8*)&Ks[row * LDP + ch * 8] = val;
        }
        __syncthreads();

        float sc[4][4];
        #pragma unroll
        for (int nb = 0; nb < 4; ++nb) {
            float4v acc = {0.f, 0.f, 0.f, 0.f};
            #pragma unroll
            for (int ks = 0; ks < 2; ++ks) {
                short8 bfrag = *(const short8*)&Ks[(nb * 16 + c) * LDP + ks * 32 + quad * 8];
                acc = __builtin_amdgcn_mfma_f32_16x16x32_bf16(qf[ks], bfrag, acc, 0, 0, 0);
            }
            #pragma unroll
            for (int r = 0; r < 4; ++r) sc[nb][r] = acc[r];
        }

        float mnew[4], alpha[4];
        #pragma unroll
        for (int r = 0; r < 4; ++r) {
            float mx = fmaxf(fmaxf(sc[0][r], sc[1][r]), fmaxf(sc[2][r], sc[3][r]));
            #pragma unroll
            for (int off = 8; off >= 1; off >>= 1) mx = fmaxf(mx, __shfl_xor(mx, off));
            mnew[r]  = fmaxf(m_r[r], mx);
            alpha[r] = __expf(m_r[r] - mnew[r]);
            m_r[r]   = mnew[r];
        }
        float psum[4] = {0.f, 0.f, 0.f, 0.f};
        #pragma unroll
        for (int nb = 0; nb < 4; ++nb)
            #pragma unroll
            for (int r = 0; r < 4; ++r) {
                float p = __expf(sc[nb][r] - mnew[r]);
                psum[r] += p;
                Pt[(wave * 16 + quad * 4 + r) * LDP + nb * 16 + c] = (short)f2bf(p);
            }
        #pragma unroll
        for (int r = 0; r < 4; ++r) {
            float s = psum[r];
            #pragma unroll
            for (int off = 8; off >= 1; off >>= 1) s += __shfl_xor(s, off);
            l_r[r] = l_r[r] * alpha[r] + s;
            #pragma unroll
            for (int nb = 0; nb < 4; ++nb) o[nb][r] *= alpha[r];
        }

        {
            const int m = tid & 7, rp = tid >> 3;
            const int r = rp * 2;
            short8 v0 = *(const short8*)(Vb + (size_t)(jt * 64 + r) * EMB + m * 8);
            short8 v1 = *(const short8*)(Vb + (size_t)(jt * 64 + r + 1) * EMB + m * 8);
            const int rch = r >> 3, rlow = r & 7;
            #pragma unroll
            for (int i = 0; i < 8; ++i) {
                const int d = m * 8 + i;
                const int col = ((rch ^ m) << 3) + rlow;
                *(int*)&Vt[d * LDP + col] =
                    (int)((unsigned)(unsigned short)v0[i] |
                          ((unsigned)(unsigned short)v1[i] << 16));
            }
        }
        __syncthreads();

        short8 pf[2];
        #pragma unroll
        for (int ks = 0; ks < 2; ++ks)
            pf[ks] = *(const short8*)&Pt[(wave * 16 + c) * LDP + ks * 32 + quad * 8];
        #pragma unroll
        for (int nb = 0; nb < 4; ++nb) {
            float4v acc = o[nb];
            #pragma unroll
            for (int ks = 0; ks < 2; ++ks) {
                const int d = nb * 16 + c;
                const int kch = ks * 4 + quad;
                const int col = ((kch ^ (d >> 3)) << 3);
                short8 vfrag = *(const short8*)&Vt[d * LDP + col];
                acc = __builtin_amdgcn_mfma_f32_16x16x32_bf16(pf[ks], vfrag, acc, 0, 0, 0);
            }
            o[nb] = acc;
        }
    }

    // ---- partial epilogue: store (m, l, o) for this KV half ----
    const size_t grb = (size_t)(b * 8 + h) * SEQ;
    #pragma unroll
    for (int r = 0; r < 4; ++r) {
        const int row = i0 + wave * 16 + quad * 4 + r;
        const size_t gr = grb + row;
        float* op = OP + (size_t)kv * 32768 * 64 + gr * 64;
        #pragma unroll
        for (int nb = 0; nb < 4; ++nb)
            op[nb * 16 + c] = o[nb][r];
        if (c == 0) {
            MP[(size_t)kv * 32768 + gr] = m_r[r];
            LP[(size_t)kv * 32768 + gr] = l_r[r];
        }
    }
}

// ---------------------------------------------------------------------------
// K2b: merge the two KV halves -> attn_bf. 2M elements, 8 cols/thread.
// ---------------------------------------------------------------------------
__global__ __launch_bounds__(256) void attn_combine_kernel(
    const float* __restrict__ OP, const float* __restrict__ MP,
    const float* __restrict__ LP, unsigned short* __restrict__ attn_bf)
{
    const int idx = blockIdx.x * 256 + threadIdx.x;   // 0..262143
    const int gr = idx >> 3;                          // 0..32767
    const int c8 = (idx & 7) * 8;
    const float m0 = MP[gr], m1 = MP[32768 + gr];
    const float l0 = LP[gr], l1 = LP[32768 + gr];
    const float m  = fmaxf(m0, m1);
    const float a0 = __expf(m0 - m), a1 = __expf(m1 - m);
    const float inv = 1.0f / (l0 * a0 + l1 * a1);
    const int bh = gr >> 10, row = gr & (SEQ - 1);
    const int b = bh >> 3, h = bh & 7;
    const float* p0 = OP + (size_t)gr * 64 + c8;
    const float* p1 = OP + (size_t)32768 * 64 + (size_t)gr * 64 + c8;
    short8 pack;
    #pragma unroll
    for (int j = 0; j < 8; ++j)
        pack[j] = (short)f2bf((p0[j] * a0 + p1[j] * a1) * inv);
    *(short8*)&attn_bf[((size_t)b * SEQ + row) * EMB + h * 64 + c8] = pack;
}

// ---------------------------------------------------------------------------
// K3: out = attn_bf @ Wo + bo (R10 body, reverted: split-K's combine cost
// exceeded its TLP gain). Reg-staged dbuf, BK=64, one barrier/iter.
// ---------------------------------------------------------------------------
__global__ __launch_bounds__(256) void out_gemm_kernel(
    const unsigned short* __restrict__ A,   // [4096][512] bf16
    const unsigned short* __restrict__ BT,  // [512][512] bf16, [n][k]
    const float* __restrict__ bias, float* __restrict__ out)
{
    __shared__ __align__(16) short As2[2][4096], Bs2[2][4096];   // 32 KB

    const int tid  = threadIdx.x;
    const int lane = tid & 63, wave = tid >> 6;
    const int qd = lane >> 4, c = lane & 15;

    // XCD-chunked bijective swizzle (512 blocks, 512%8==0).
    const int phys = blockIdx.x + 8 * blockIdx.y;
    const int logical = (phys & 7) * 64 + (phys >> 3);
    const int bx = logical & 7, by = logical >> 3;
    const int row0 = by * 64, col0 = bx * 64;

    // staging map: thread -> row sr, chunk pair {sj, sj+1} (32B contiguous)
    const int sr = tid >> 2, sj = (tid & 3) * 2;
    const size_t gA = (size_t)(row0 + sr) * EMB + sj * 8;
    const size_t gB = (size_t)(col0 + sr) * EMB + sj * 8;
    const int dA0 = sr * 64 + ((sj ^ (sr & 7)) * 8);
    const int dA1 = sr * 64 + (((sj + 1) ^ (sr & 7)) * 8);

    // frag read offsets: row R, logical chunk kk*4+qd -> slot ^(c&7)
    int arf[2], brf[4][2];
    #pragma unroll
    for (int kk = 0; kk < 2; ++kk) {
        arf[kk] = (wave * 16 + c) * 64 + (((kk * 4 + qd) ^ (c & 7)) * 8);
        #pragma unroll
        for (int j = 0; j < 4; ++j)
            brf[j][kk] = (j * 16 + c) * 64 + (((kk * 4 + qd) ^ (c & 7)) * 8);
    }

    float4v acc[4];
    #pragma unroll
    for (int j = 0; j < 4; ++j) acc[j] = (float4v){0.f, 0.f, 0.f, 0.f};

    short8 ra0, ra1, rb0, rb1;
    ra0 = *(const short8*)&A[gA];      ra1 = *(const short8*)&A[gA + 8];
    rb0 = *(const short8*)&BT[gB];     rb1 = *(const short8*)&BT[gB + 8];
    *(short8*)&As2[0][dA0] = ra0; *(short8*)&As2[0][dA1] = ra1;
    *(short8*)&Bs2[0][dA0] = rb0; *(short8*)&Bs2[0][dA1] = rb1;

    for (int it = 0; it < 8; ++it) {
        __syncthreads();
        const int cur = it & 1;
        if (it < 7) {
            const int k0 = (it + 1) * 64;
            ra0 = *(const short8*)&A[gA + k0];  ra1 = *(const short8*)&A[gA + k0 + 8];
            rb0 = *(const short8*)&BT[gB + k0]; rb1 = *(const short8*)&BT[gB + k0 + 8];
        }
        #pragma unroll
        for (int kk = 0; kk < 2; ++kk) {
            const short8 af = *(const short8*)&As2[cur][arf[kk]];
            #pragma unroll
            for (int j = 0; j < 4; ++j) {
                const short8 bf = *(const short8*)&Bs2[cur][brf[j][kk]];
                acc[j] = __builtin_amdgcn_mfma_f32_16x16x32_bf16(af, bf, acc[j], 0, 0, 0);
            }
        }
        if (it < 7) {
            const int nxt = cur ^ 1;
            *(short8*)&As2[nxt][dA0] = ra0; *(short8*)&As2[nxt][dA1] = ra1;
            *(short8*)&Bs2[nxt][dA0] = rb0; *(short8*)&Bs2[nxt][dA1] = rb1;
        }
    }

    #pragma unroll
    for (int j = 0; j < 4; ++j)
        #pragma unroll
        for (int r = 0; r < 4; ++r) {
            const int gm = row0 + wave * 16 + qd * 4 + r;
            const int gn = col0 + j * 16 + c;
            out[(size_t)gm * EMB + gn] = acc[j][r] + bias[gn];
        }
}

// ---------------------------------------------------------------------------
extern "C" void kernel_launch(void* const* d_in, const int* in_sizes, int n_in,
                              void* d_out, int out_size, void* d_ws, size_t ws_size,
                              hipStream_t stream)
{
    const float* x   = (const float*)d_in[0];
    const float* Wq  = (const float*)d_in[1];
    const float* Wk  = (const float*)d_in[2];
    const float* Wv  = (const float*)d_in[3];
    const float* Wo  = (const float*)d_in[4];
    const float* bo  = (const float*)d_in[5];
    const float* gW1 = (const float*)d_in[6];
    const float* gb1 = (const float*)d_in[7];
    const float* gg  = (const float*)d_in[8];
    const float* gbe = (const float*)d_in[9];
    const float* gW2 = (const float*)d_in[10];
    const float* gb2 = (const float*)d_in[11];
    const float* gW3 = (const float*)d_in[12];
    const float* gb3 = (const float*)d_in[13];
    const float* cW1 = (const float*)d_in[14];
    const float* cb1 = (const float*)d_in[15];
    const float* cg  = (const float*)d_in[16];
    const float* cbe = (const float*)d_in[17];
    const float* cW2 = (const float*)d_in[18];
    const float* cb2 = (const float*)d_in[19];
    const float* cW3 = (const float*)d_in[20];
    const float* cb3 = (const float*)d_in[21];
    const float* aq  = (const float*)d_in[22];
    const float* bq  = (const float*)d_in[23];
    const float* ak  = (const float*)d_in[24];
    const float* bk  = (const float*)d_in[25];
    const float* av  = (const float*)d_in[26];
    const float* bv  = (const float*)d_in[27];

    unsigned short* q_sum   = (unsigned short*)((char*)d_ws + 16384);
    unsigned short* k_sum   = q_sum   + (size_t)NROWS * EMB;
    unsigned short* v_mean  = k_sum   + (size_t)NROWS * EMB;
    unsigned short* attn_bf = v_mean  + (size_t)NROWS * EMB;
    unsigned short* WoT     = attn_bf + (size_t)NROWS * EMB;
    unsigned short* WL      = WoT     + (size_t)EMB * EMB;     // 3z x 3limb x [512][512] bf16
    unsigned short* XLp     = WL      + (size_t)9 * EMB * EMB; // 3limb x [4096][512] bf16
    double* scores          = (double*)(XLp + (size_t)3 * NROWS * EMB); // [2][4096] f64
    float* OP               = (float*)(scores + 2 * NROWS);    // [2][32768][64] f32, 16 MB
    float* MP               = OP + (size_t)2 * 32768 * 64;     // [2][32768]
    float* LP               = MP + (size_t)2 * 32768;          // [2][32768]
    float* out = (float*)d_out;

    pre_kernel<<<dim3(3328), dim3(256), 0, stream>>>(
        x, gW1, gb1, gg, gbe, gW2, gb2, gW3, gb3,
        cW1, cb1, cg, cbe, cW2, cb2, cW3, cb3, scores,
        Wq, Wk, Wv, WL, XLp, Wo, WoT);

    qkv_mfma_lif_kernel<<<dim3(EMB / 64, NROWS / 128, 3), dim3(256), 0, stream>>>(
        XLp, WL, aq, bq, ak, bk, av, bv, scores, q_sum, k_sum, v_mean);

    attn_mfma_kernel<<<dim3(SEQ / 64, 8, 8), dim3(256), 0, stream>>>(
        q_sum, k_sum, v_mean, OP, MP, LP);

    attn_combine_kernel<<<dim3(1024), dim3(256), 0, stream>>>(
        OP, MP, LP, attn_bf);

    out_gemm_kernel<<<dim3(EMB / 64, NROWS / 64), dim3(256), 0, stream>>>(
        attn_bf, WoT, bo, out);
}

// Round 13
// 247.132 us; speedup vs baseline: 1.0753x; 1.0254x over previous
//
#include <hip/hip_runtime.h>
#include <math.h>

// Problem constants (B=4, S=1024, E=512, H=8, D=64, T_MAX=20)
#define SEQ   1024
#define EMB   512
#define NROWS 4096   // B*S
#define LDP   72     // attn LDS row stride (bf16 elems)
#define GROWS 4      // gates rows per block

typedef __attribute__((ext_vector_type(8))) short short8;    // bf16 x8 MFMA frag
typedef __attribute__((ext_vector_type(4))) float float4v;   // f32 x4 MFMA acc

__device__ __forceinline__ float bf2f(unsigned short s) {
    union { float f; unsigned u; } x; x.u = ((unsigned)s) << 16; return x.f;
}
__device__ __forceinline__ unsigned short f2bf(float f) {
    union { float f; unsigned u; } x; x.f = f;
    unsigned r = x.u + 0x7fffu + ((x.u >> 16) & 1u);   // round-to-nearest-even
    return (unsigned short)(r >> 16);
}

// async global->LDS 16B: LDS dest = wave-uniform base + lane*16 (HW rule).
__device__ __forceinline__ void gld16(const unsigned short* g, short* l) {
    __builtin_amdgcn_global_load_lds(
        (__attribute__((address_space(1))) void*)(g),
        (__attribute__((address_space(3))) void*)(l), 16, 0, 0);
}

// 3-limb bf16 split: x ~= h + m + l. Residual subtractions are Sterbenz-exact,
// so h+m+l carries ~26 mantissa bits of x; per-limb repr error <= 2^-27 |x|.
__device__ __forceinline__ void split3(float x, unsigned short& h, unsigned short& m, unsigned short& l) {
    union { float f; unsigned u; } a; a.f = x;
    const unsigned rh = a.u + 0x7fffu + ((a.u >> 16) & 1u);
    h = (unsigned short)(rh >> 16);
    union { float f; unsigned u; } hf; hf.u = rh & 0xffff0000u;
    const float r1 = x - hf.f;                 // exact
    a.f = r1;
    const unsigned rm = a.u + 0x7fffu + ((a.u >> 16) & 1u);
    m = (unsigned short)(rm >> 16);
    union { float f; unsigned u; } mf; mf.u = rm & 0xffff0000u;
    const float r2 = r1 - mf.f;                // exact
    l = f2bf(r2);
}

// ---------------------------------------------------------------------------
// gate/complexity MLP evaluator (R6 form: split-K GEMM1, 1 W1 load -> 4 FMAs;
// math bit-identical to the R4/R6-passing kernels).
// ---------------------------------------------------------------------------
template<int H1, int H2>
__device__ __forceinline__ double mlp_eval(
    const double xs[GROWS][EMB], double* h1, double* h2, double* red,
    double* mu_s, double* var_s,
    const float* __restrict__ W1, const float* __restrict__ b1,
    const float* __restrict__ gam, const float* __restrict__ bet,
    const float* __restrict__ W2, const float* __restrict__ b2,
    const float* __restrict__ W3, const float* __restrict__ b3,
    int tid, int myrow)
{
    constexpr int S  = 256 / H1;    // k-slices: 2 (gate), 4 (complexity)
    constexpr int KS = EMB / S;     // 256 or 128

    {   // h1 partials: thread = (col, k-slice), 4-row ILP
        const int col = tid % H1, sk = tid / H1;
        double acc[GROWS] = {0.0, 0.0, 0.0, 0.0};
        const int kbeg = sk * KS;
        #pragma unroll 4
        for (int k = kbeg; k < kbeg + KS; ++k) {
            const double w = (double)W1[k * H1 + col];
            #pragma unroll
            for (int r = 0; r < GROWS; ++r) acc[r] += w * xs[r][k];
        }
        #pragma unroll
        for (int r = 0; r < GROWS; ++r) red[(sk * GROWS + r) * H1 + col] = acc[r];
    }
    __syncthreads();
    for (int idx = tid; idx < GROWS * H1; idx += 256) {   // reduce + bias
        const int r = idx / H1, cc = idx % H1;
        double s = 0.0;
        #pragma unroll
        for (int t = 0; t < S; ++t) s += red[(t * GROWS + r) * H1 + cc];
        h1[r * H1 + cc] = s + (double)b1[cc];
    }
    __syncthreads();

    {   // mean: wave w owns row w
        const int w = tid >> 6, l = tid & 63;
        double s = 0.0;
        for (int c = l; c < H1; c += 64) s += h1[w * H1 + c];
        #pragma unroll
        for (int off = 32; off >= 1; off >>= 1) s += __shfl_xor(s, off);
        if (l == 0) mu_s[w] = s / (double)H1;
    }
    __syncthreads();
    {   // var
        const int w = tid >> 6, l = tid & 63;
        const double mu = mu_s[w];
        double s = 0.0;
        for (int c = l; c < H1; c += 64) { const double d = h1[w * H1 + c] - mu; s += d * d; }
        #pragma unroll
        for (int off = 32; off >= 1; off >>= 1) s += __shfl_xor(s, off);
        if (l == 0) var_s[w] = s / (double)H1;
    }
    __syncthreads();
    // normalize + relu
    for (int idx = tid; idx < GROWS * H1; idx += 256) {
        const int r = idx / H1, cc = idx % H1;
        double hn = (h1[r * H1 + cc] - mu_s[r]) / sqrt(var_s[r] + 1e-5) * (double)gam[cc] + (double)bet[cc];
        h1[r * H1 + cc] = hn > 0.0 ? hn : 0.0;
    }
    __syncthreads();

    {   // h2 = relu(h1 @ W2 + b2)
        const int col = tid % H2;
        const int r   = tid / H2;
        if (r < GROWS) {
            double acc = (double)b2[col];
            for (int k = 0; k < H1; ++k)
                acc += (double)W2[k * H2 + col] * h1[r * H1 + k];
            h2[r * H2 + col] = acc > 0.0 ? acc : 0.0;
        }
    }
    __syncthreads();

    {   // scalar = h2 @ W3: wave w owns row w
        const int w = tid >> 6, l = tid & 63;
        double s = 0.0;
        for (int c = l; c < H2; c += 64) s += h2[w * H2 + c] * (double)W3[c];
        #pragma unroll
        for (int off = 32; off >= 1; off >>= 1) s += __shfl_xor(s, off);
        if (l == 0) mu_s[w] = s;   // reuse as scratch
    }
    __syncthreads();
    double ret = 0.0;
    if (myrow >= 0) {
        const double z = mu_s[myrow] + (double)b3[0];
        ret = 1.0 / (1.0 + exp(-z));
    }
    return ret;
}

// ---------------------------------------------------------------------------
// K0: fused pre-kernel: gates / x_limbs / w_limbs / wot.
// ---------------------------------------------------------------------------
__global__ __launch_bounds__(256) void pre_kernel(
    const float* __restrict__ x,
    const float* __restrict__ gW1, const float* __restrict__ gb1,
    const float* __restrict__ gg,  const float* __restrict__ gbe,
    const float* __restrict__ gW2, const float* __restrict__ gb2,
    const float* __restrict__ gW3, const float* __restrict__ gb3,
    const float* __restrict__ cW1, const float* __restrict__ cb1,
    const float* __restrict__ cg,  const float* __restrict__ cbe,
    const float* __restrict__ cW2, const float* __restrict__ cb2,
    const float* __restrict__ cW3, const float* __restrict__ cb3,
    double* __restrict__ scores,
    const float* __restrict__ Wq, const float* __restrict__ Wk,
    const float* __restrict__ Wv, unsigned short* __restrict__ WL,
    unsigned short* __restrict__ XL,
    const float* __restrict__ Wo, unsigned short* __restrict__ WoT)
{
    __shared__ __align__(16) char smem[30784];
    const int bid = blockIdx.x;
    const int tid = threadIdx.x;

    if (bid < 2048) {
        // ---- gates ----
        double (*xs)[EMB] = (double(*)[EMB])smem;            // 16384 B
        double* h1    = (double*)(smem + 16384);             // 4096 B
        double* h2    = (double*)(smem + 20480);             // 2048 B
        double* red   = (double*)(smem + 22528);             // 8192 B
        double* mu_s  = (double*)(smem + 30720);
        double* var_s = (double*)(smem + 30752);

        const int gx = bid & 1023, gy = bid >> 10;
        const int row0 = gx * GROWS;

        for (int idx = tid; idx < GROWS * EMB; idx += 256) {
            const int r = idx >> 9, cc = idx & 511;
            xs[r][cc] = (double)x[(size_t)(row0 + r) * EMB + cc];
        }
        __syncthreads();

        const int myrow = (tid < GROWS) ? tid : -1;
        double v;
        if (gy == 0)
            v = mlp_eval<128, 64>(xs, h1, h2, red, mu_s, var_s,
                                  gW1, gb1, gg, gbe, gW2, gb2, gW3, gb3, tid, myrow);
        else
            v = mlp_eval<64, 32>(xs, h1, h2, red, mu_s, var_s,
                                 cW1, cb1, cg, cbe, cW2, cb2, cW3, cb3, tid, myrow);

        if (myrow >= 0)
            scores[(size_t)gy * NROWS + row0 + myrow] = v;

    } else if (bid < 3072) {
        // ---- x limb prep ----
        unsigned short* Xh = XL;
        unsigned short* Xm = XL + (size_t)NROWS * EMB;
        unsigned short* Xl = Xm + (size_t)NROWS * EMB;
        const size_t i0 = ((size_t)(bid - 2048) * 256 + tid) * 8;
        const float4 a0 = *(const float4*)&x[i0];
        const float4 a1 = *(const float4*)&x[i0 + 4];
        const float av8[8] = {a0.x, a0.y, a0.z, a0.w, a1.x, a1.y, a1.z, a1.w};
        short8 ph, pm, pl;
        #pragma unroll
        for (int e = 0; e < 8; ++e) {
            unsigned short h, m, l;
            split3(av8[e], h, m, l);
            ph[e] = (short)h; pm[e] = (short)m; pl[e] = (short)l;
        }
        *(short8*)&Xh[i0] = ph;
        *(short8*)&Xm[i0] = pm;
        *(short8*)&Xl[i0] = pl;

    } else if (bid < 3264) {
        // ---- W^T limb prep ----
        const int t = bid - 3072;
        const int z = t >> 6, rem = t & 63;
        const int k0 = (rem >> 3) * 64, n0 = (rem & 7) * 64;
        const float* __restrict__ W = (z == 0) ? Wq : (z == 1) ? Wk : Wv;
        unsigned short* Th = WL + (size_t)z * 3 * EMB * EMB;
        unsigned short* Tm = Th + (size_t)EMB * EMB;
        unsigned short* Tl = Tm + (size_t)EMB * EMB;

        float (*Ws)[68] = (float(*)[68])smem;   // 17408 B
        #pragma unroll
        for (int it = 0; it < 4; ++it) {
            const int idx = it * 256 + tid;
            const int r = idx >> 4, c4 = (idx & 15) * 4;
            *(float4*)&Ws[r][c4] = *(const float4*)&W[(size_t)(k0 + r) * EMB + n0 + c4];
        }
        __syncthreads();
        #pragma unroll
        for (int it = 0; it < 2; ++it) {
            const int idx = it * 256 + tid;
            const int n = idx >> 3, k8 = (idx & 7) * 8;
            short8 ph, pm, pl;
            #pragma unroll
            for (int j = 0; j < 8; ++j) {
                unsigned short h, m, l;
                split3(Ws[k8 + j][n], h, m, l);
                ph[j] = (short)h; pm[j] = (short)m; pl[j] = (short)l;
            }
            const size_t o = (size_t)(n0 + n) * EMB + k0 + k8;
            *(short8*)&Th[o] = ph;
            *(short8*)&Tm[o] = pm;
            *(short8*)&Tl[o] = pl;
        }

    } else {
        // ---- Wo^T bf16 prep ----
        const int t = bid - 3264;
        const int k0 = (t >> 3) * 64, n0 = (t & 7) * 64;
        unsigned short (*Ws)[72] = (unsigned short(*)[72])smem;   // 9216 B
        #pragma unroll
        for (int it = 0; it < 4; ++it) {
            const int idx = it * 256 + tid;
            const int r = idx >> 4, c4 = (idx & 15) * 4;
            const float4 w4 = *(const float4*)&Wo[(size_t)(k0 + r) * EMB + n0 + c4];
            Ws[r][c4 + 0] = f2bf(w4.x); Ws[r][c4 + 1] = f2bf(w4.y);
            Ws[r][c4 + 2] = f2bf(w4.z); Ws[r][c4 + 3] = f2bf(w4.w);
        }
        __syncthreads();
        #pragma unroll
        for (int it = 0; it < 2; ++it) {
            const int idx = it * 256 + tid;
            const int n = idx >> 3, k8 = (idx & 7) * 8;
            short8 pack;
            #pragma unroll
            for (int j = 0; j < 8; ++j) pack[j] = (short)Ws[k8 + j][n];
            *(short8*)&WoT[(size_t)(n0 + n) * EMB + k0 + k8] = pack;
        }
    }
}

// ---------------------------------------------------------------------------
// K1: QKV GEMM, 3-limb split-bf16 MFMA (R6/R9 body, unchanged).
// ---------------------------------------------------------------------------
__global__ __launch_bounds__(256) void qkv_mfma_lif_kernel(
    const unsigned short* __restrict__ XL, const unsigned short* __restrict__ WL,
    const float* __restrict__ aq, const float* __restrict__ bq,
    const float* __restrict__ akp, const float* __restrict__ bkp,
    const float* __restrict__ av, const float* __restrict__ bv,
    const double* __restrict__ scores,
    unsigned short* __restrict__ q_sum, unsigned short* __restrict__ k_sum,
    unsigned short* __restrict__ v_mean)
{
    const int z = blockIdx.z;
    const unsigned short* __restrict__ WTh = WL + (size_t)z * 3 * EMB * EMB;
    const unsigned short* __restrict__ WTm = WTh + (size_t)EMB * EMB;
    const unsigned short* __restrict__ WTl = WTm + (size_t)EMB * EMB;
    const unsigned short* __restrict__ Xh = XL;
    const unsigned short* __restrict__ Xm = XL + (size_t)NROWS * EMB;
    const unsigned short* __restrict__ Xl = Xm + (size_t)NROWS * EMB;
    unsigned short* __restrict__ out = (z == 0) ? q_sum : (z == 1) ? k_sum : v_mean;
    const double alpha = (double)((z == 0) ? aq : (z == 1) ? akp : av)[0];
    const double beta  = (double)((z == 0) ? bq : (z == 1) ? bkp : bv)[0];

    // XCD-chunked bijective swizzle within this z (256 blocks, 256%8==0).
    const int phys = blockIdx.x + 8 * blockIdx.y;
    const int logical = (phys & 7) * 32 + (phys >> 3);
    const int bx = logical & 7, by = logical >> 3;
    const int row0 = by * 128, col0 = bx * 64;

    // limb planes h/m/l; rows of 32 bf16 (64 B), XOR chunk swizzle, no pad.
    __shared__ __align__(16) short As[3][4096];   // 24 KB
    __shared__ __align__(16) short Bs[3][2048];   // 12 KB

    const int tid  = threadIdx.x;
    const int lane = tid & 63, wave = tid >> 6;
    const int qd = lane >> 4, c = lane & 15;
    const int wrow = wave * 32;

    // global_load_lds source offsets (lane-only chunk permutation)
    const int kc8 = ((lane & 3) ^ ((lane >> 3) & 3)) * 8;
    const size_t ga0 = (size_t)(row0 + wave * 16 + (lane >> 2)) * EMB + kc8;       // A q=0
    const size_t ga1 = ga0 + (size_t)64 * EMB;                                     // A q=1
    const size_t gb  = (size_t)(col0 + wave * 16 + (lane >> 2)) * EMB + kc8;       // B

    // frag read offsets (row R, k-chunk qd -> slot qd^((R>>1)&3))
    int arf[2], brf[4];
    #pragma unroll
    for (int i = 0; i < 2; ++i) {
        const int Ra = wrow + i * 16 + c;
        arf[i] = Ra * 32 + ((qd ^ ((Ra >> 1) & 3)) * 8);
    }
    #pragma unroll
    for (int j = 0; j < 4; ++j) {
        const int Rb = j * 16 + c;
        brf[j] = Rb * 32 + ((qd ^ ((Rb >> 1) & 3)) * 8);
    }

    float4v acc[2][4];
    #pragma unroll
    for (int i = 0; i < 2; ++i)
        #pragma unroll
        for (int j = 0; j < 4; ++j)
            acc[i][j] = (float4v){0.f, 0.f, 0.f, 0.f};

    for (int k0 = 0; k0 < EMB; k0 += 32) {
        __syncthreads();   // prior iteration's frag reads complete
        gld16(Xh  + ga0 + k0, &As[0][wave * 512]);
        gld16(Xh  + ga1 + k0, &As[0][2048 + wave * 512]);
        gld16(Xm  + ga0 + k0, &As[1][wave * 512]);
        gld16(Xm  + ga1 + k0, &As[1][2048 + wave * 512]);
        gld16(Xl  + ga0 + k0, &As[2][wave * 512]);
        gld16(Xl  + ga1 + k0, &As[2][2048 + wave * 512]);
        gld16(WTh + gb  + k0, &Bs[0][wave * 512]);
        gld16(WTm + gb  + k0, &Bs[1][wave * 512]);
        gld16(WTl + gb  + k0, &Bs[2][wave * 512]);
        __syncthreads();   // drains vmcnt -> tile visible

        short8 Afh[2], Afm[2], Afl[2];
        #pragma unroll
        for (int i = 0; i < 2; ++i) {
            Afh[i] = *(const short8*)&As[0][arf[i]];
            Afm[i] = *(const short8*)&As[1][arf[i]];
            Afl[i] = *(const short8*)&As[2][arf[i]];
        }
        short8 Bfh[4], Bfm[4], Bfl[4];
        #pragma unroll
        for (int j = 0; j < 4; ++j) {
            Bfh[j] = *(const short8*)&Bs[0][brf[j]];
            Bfm[j] = *(const short8*)&Bs[1][brf[j]];
            Bfl[j] = *(const short8*)&Bs[2][brf[j]];
        }

        #pragma unroll
        for (int i = 0; i < 2; ++i)
            #pragma unroll
            for (int j = 0; j < 4; ++j) {
                float4v t = acc[i][j];
                t = __builtin_amdgcn_mfma_f32_16x16x32_bf16(Afh[i], Bfh[j], t, 0, 0, 0);
                t = __builtin_amdgcn_mfma_f32_16x16x32_bf16(Afh[i], Bfm[j], t, 0, 0, 0);
                t = __builtin_amdgcn_mfma_f32_16x16x32_bf16(Afm[i], Bfh[j], t, 0, 0, 0);
                t = __builtin_amdgcn_mfma_f32_16x16x32_bf16(Afm[i], Bfm[j], t, 0, 0, 0);
                t = __builtin_amdgcn_mfma_f32_16x16x32_bf16(Afh[i], Bfl[j], t, 0, 0, 0);
                t = __builtin_amdgcn_mfma_f32_16x16x32_bf16(Afl[i], Bfh[j], t, 0, 0, 0);
                acc[i][j] = t;
            }
    }

    // ---- LIF epilogue: f64, per-element op order identical to the passing
    // version; 4 cols of a row (same T) run as 4 independent chains.
    #pragma unroll
    for (int i = 0; i < 2; ++i)
        #pragma unroll
        for (int r = 0; r < 4; ++r) {
            const int gm = row0 + wrow + i * 16 + qd * 4 + r;
            const double g0 = scores[gm];
            const double c0 = scores[NROWS + gm];
            const int s = gm & (SEQ - 1);
            const double step = (1.2 - 0.8) / (double)(SEQ - 1);   // np.linspace step
            const double pos  = (double)s * step + 0.8;
            const double score = ((1.0 - 0.3) * g0 + 0.3 * c0) * pos;
            double td = ceil(score * 20.0);
            td = td < 1.0 ? 1.0 : (td > 20.0 ? 20.0 : td);
            const int T = (int)td;
            double cur0 = 0.0, cur1 = 0.0, cur2 = 0.0, cur3 = 0.0;
            double vm0 = 0.0, vm1 = 0.0, vm2 = 0.0, vm3 = 0.0;
            double sp0 = 0.0, sp1 = 0.0, sp2 = 0.0, sp3 = 0.0;
            const double xv0 = (double)acc[i][0][r];
            const double xv1 = (double)acc[i][1][r];
            const double xv2 = (double)acc[i][2][r];
            const double xv3 = (double)acc[i][3][r];
            for (int t = 0; t < T; ++t) {
                cur0 = alpha * cur0 + xv0; vm0 = beta * vm0 + cur0;
                if (vm0 >= 1.0) { sp0 += 1.0; vm0 = 0.0; }
                cur1 = alpha * cur1 + xv1; vm1 = beta * vm1 + cur1;
                if (vm1 >= 1.0) { sp1 += 1.0; vm1 = 0.0; }
                cur2 = alpha * cur2 + xv2; vm2 = beta * vm2 + cur2;
                if (vm2 >= 1.0) { sp2 += 1.0; vm2 = 0.0; }
                cur3 = alpha * cur3 + xv3; vm3 = beta * vm3 + cur3;
                if (vm3 >= 1.0) { sp3 += 1.0; vm3 = 0.0; }
            }
            if (z == 2) { sp0 /= 20.0; sp1 /= 20.0; sp2 /= 20.0; sp3 /= 20.0; }
            const size_t ob = (size_t)gm * EMB + col0 + c;
            out[ob +  0] = f2bf((float)sp0);
            out[ob + 16] = f2bf((float)sp1);
            out[ob + 32] = f2bf((float)sp2);
            out[ob + 48] = f2bf((float)sp3);
        }
}

// ---------------------------------------------------------------------------
// K2: fused flash-style MFMA attention (R10 body: one barrier per jt via
// double-buffered Ks+Vt, T14 async-stage; bit-identical output).
// ---------------------------------------------------------------------------
__global__ __launch_bounds__(256) void attn_mfma_kernel(
    const unsigned short* __restrict__ q, const unsigned short* __restrict__ k,
    const unsigned short* __restrict__ v, unsigned short* __restrict__ attn_bf)
{
    __shared__ __align__(16) short Ks2[2][64 * LDP];
    __shared__ __align__(16) short Vt2[2][64 * LDP];
    __shared__ __align__(16) short Pt[64 * LDP];

    const int b = blockIdx.z, h = blockIdx.y;
    const int i0 = blockIdx.x * 64;
    const int tid  = threadIdx.x;
    const int wave = tid >> 6, lane = tid & 63;
    const int quad = lane >> 4, c = lane & 15;

    const unsigned short* Qb = q + ((size_t)b * SEQ + i0) * EMB + h * 64;
    const unsigned short* Kb = k + (size_t)b * SEQ * EMB + h * 64;
    const unsigned short* Vb = v + (size_t)b * SEQ * EMB + h * 64;

    short8 qf[2];
    {
        const int qrow = wave * 16 + c;
        #pragma unroll
        for (int ks = 0; ks < 2; ++ks) {
            short8 raw = *(const short8*)(Qb + (size_t)qrow * EMB + ks * 32 + quad * 8);
            short8 sc8;
            #pragma unroll
            for (int j = 0; j < 8; ++j)
                sc8[j] = (short)f2bf(bf2f((unsigned short)raw[j]) * 0.125f);
            qf[ks] = sc8;
        }
    }

    // staging thread maps
    const int krow = tid >> 3, kch = tid & 7;
    const int vm_  = tid & 7,  vrp = tid >> 3;
    const int vr   = vrp * 2;
    const int vrch = vr >> 3, vrlow = vr & 7;

    short8 kr0, kr1, vv0, vv1;
    kr0 = *(const short8*)(Kb + (size_t)krow * EMB + kch * 8);
    kr1 = *(const short8*)(Kb + (size_t)(32 + krow) * EMB + kch * 8);
    vv0 = *(const short8*)(Vb + (size_t)vr * EMB + vm_ * 8);
    vv1 = *(const short8*)(Vb + (size_t)(vr + 1) * EMB + vm_ * 8);
    {
        *(short8*)&Ks2[0][krow * LDP + kch * 8] = kr0;
        *(short8*)&Ks2[0][(32 + krow) * LDP + kch * 8] = kr1;
        #pragma unroll
        for (int i = 0; i < 8; ++i) {
            const int d = vm_ * 8 + i;
            const int col = ((vrch ^ vm_) << 3) + vrlow;
            *(int*)&Vt2[0][d * LDP + col] =
                (int)((unsigned)(unsigned short)vv0[i] |
                      ((unsigned)(unsigned short)vv1[i] << 16));
        }
    }

    float m_r[4], l_r[4];
    float4v o[4];
    #pragma unroll
    for (int r = 0; r < 4; ++r) { m_r[r] = -1e30f; l_r[r] = 0.f; }
    #pragma unroll
    for (int nb = 0; nb < 4; ++nb)
        #pragma unroll
        for (int r = 0; r < 4; ++r) o[nb][r] = 0.f;

    for (int jt = 0; jt < SEQ / 64; ++jt) {
        __syncthreads();
        const short* Ks = &Ks2[jt & 1][0];
        const short* Vt = &Vt2[jt & 1][0];

        if (jt + 1 < SEQ / 64) {
            const size_t kb = (size_t)((jt + 1) * 64);
            kr0 = *(const short8*)(Kb + (kb + krow) * EMB + kch * 8);
            kr1 = *(const short8*)(Kb + (kb + 32 + krow) * EMB + kch * 8);
            vv0 = *(const short8*)(Vb + (kb + vr) * EMB + vm_ * 8);
            vv1 = *(const short8*)(Vb + (kb + vr + 1) * EMB + vm_ * 8);
        }

        float sc[4][4];
        #pragma unroll
        for (int nb = 0; nb < 4; ++nb) {
            float4v acc = {0.f, 0.f, 0.f, 0.f};
            #pragma unroll
            for (int ks = 0; ks < 2; ++ks) {
                short8 bfrag = *(const short8*)&Ks[(nb * 16 + c) * LDP + ks * 32 + quad * 8];
                acc = __builtin_amdgcn_mfma_f32_16x16x32_bf16(qf[ks], bfrag, acc, 0, 0, 0);
            }
            #pragma unroll
            for (int r = 0; r < 4; ++r) sc[nb][r] = acc[r];
        }

        float mnew[4], alpha[4];
        #pragma unroll
        for (int r = 0; r < 4; ++r) {
            float mx = fmaxf(fmaxf(sc[0][r], sc[1][r]), fmaxf(sc[2][r], sc[3][r]));
            #pragma unroll
            for (int off = 8; off >= 1; off >>= 1) mx = fmaxf(mx, __shfl_xor(mx, off));
            mnew[r]  = fmaxf(m_r[r], mx);
            alpha[r] = __expf(m_r[r] - mnew[r]);
            m_r[r]   = mnew[r];
        }
        float psum[4] = {0.f, 0.f, 0.f, 0.f};
        #pragma unroll
        for (int nb = 0; nb < 4; ++nb)
            #pragma unroll
            for (int r = 0; r < 4; ++r) {
                float p = __expf(sc[nb][r] - mnew[r]);
                psum[r] += p;
                Pt[(wave * 16 + quad * 4 + r) * LDP + nb * 16 + c] = (short)f2bf(p);
            }
        #pragma unroll
        for (int r = 0; r < 4; ++r) {
            float s = psum[r];
            #pragma unroll
            for (int off = 8; off >= 1; off >>= 1) s += __shfl_xor(s, off);
            l_r[r] = l_r[r] * alpha[r] + s;
            #pragma unroll
            for (int nb = 0; nb < 4; ++nb) o[nb][r] *= alpha[r];
        }

        short8 pf[2];
        #pragma unroll
        for (int ks = 0; ks < 2; ++ks)
            pf[ks] = *(const short8*)&Pt[(wave * 16 + c) * LDP + ks * 32 + quad * 8];
        #pragma unroll
        for (int nb = 0; nb < 4; ++nb) {
            float4v acc = o[nb];
            #pragma unroll
            for (int ks = 0; ks < 2; ++ks) {
                const int d = nb * 16 + c;
                const int kch2 = ks * 4 + quad;
                const int col = ((kch2 ^ (d >> 3)) << 3);
                short8 vfrag = *(const short8*)&Vt[d * LDP + col];
                acc = __builtin_amdgcn_mfma_f32_16x16x32_bf16(pf[ks], vfrag, acc, 0, 0, 0);
            }
            o[nb] = acc;
        }

        if (jt + 1 < SEQ / 64) {
            const int nb2 = (jt + 1) & 1;
            *(short8*)&Ks2[nb2][krow * LDP + kch * 8] = kr0;
            *(short8*)&Ks2[nb2][(32 + krow) * LDP + kch * 8] = kr1;
            #pragma unroll
            for (int i = 0; i < 8; ++i) {
                const int d = vm_ * 8 + i;
                const int col = ((vrch ^ vm_) << 3) + vrlow;
                *(int*)&Vt2[nb2][d * LDP + col] =
                    (int)((unsigned)(unsigned short)vv0[i] |
                          ((unsigned)(unsigned short)vv1[i] << 16));
            }
        }
    }

    #pragma unroll
    for (int r = 0; r < 4; ++r) {
        const float inv = 1.0f / l_r[r];
        const int row = i0 + wave * 16 + quad * 4 + r;
        #pragma unroll
        for (int nb = 0; nb < 4; ++nb)
            attn_bf[((size_t)b * SEQ + row) * EMB + h * 64 + nb * 16 + c] =
                f2bf(o[nb][r] * inv);
    }
}

// ---------------------------------------------------------------------------
// K3: out = attn_bf @ Wo + bo (R10 body: reg-staged dbuf, BK=64, one
// barrier/iter, XCD swizzle; bit-identical results).
// ---------------------------------------------------------------------------
__global__ __launch_bounds__(256) void out_gemm_kernel(
    const unsigned short* __restrict__ A,   // [4096][512] bf16
    const unsigned short* __restrict__ BT,  // [512][512] bf16, [n][k]
    const float* __restrict__ bias, float* __restrict__ out)
{
    __shared__ __align__(16) short As2[2][4096], Bs2[2][4096];   // 32 KB

    const int tid  = threadIdx.x;
    const int lane = tid & 63, wave = tid >> 6;
    const int qd = lane >> 4, c = lane & 15;

    // XCD-chunked bijective swizzle (512 blocks, 512%8==0).
    const int phys = blockIdx.x + 8 * blockIdx.y;
    const int logical = (phys & 7) * 64 + (phys >> 3);
    const int bx = logical & 7, by = logical >> 3;
    const int row0 = by * 64, col0 = bx * 64;

    // staging map: thread -> row sr, chunk pair {sj, sj+1} (32B contiguous)
    const int sr = tid >> 2, sj = (tid & 3) * 2;
    const size_t gA = (size_t)(row0 + sr) * EMB + sj * 8;
    const size_t gB = (size_t)(col0 + sr) * EMB + sj * 8;
    const int dA0 = sr * 64 + ((sj ^ (sr & 7)) * 8);
    const int dA1 = sr * 64 + (((sj + 1) ^ (sr & 7)) * 8);

    // frag read offsets: row R, logical chunk kk*4+qd -> slot ^(c&7)
    int arf[2], brf[4][2];
    #pragma unroll
    for (int kk = 0; kk < 2; ++kk) {
        arf[kk] = (wave * 16 + c) * 64 + (((kk * 4 + qd) ^ (c & 7)) * 8);
        #pragma unroll
        for (int j = 0; j < 4; ++j)
            brf[j][kk] = (j * 16 + c) * 64 + (((kk * 4 + qd) ^ (c & 7)) * 8);
    }

    float4v acc[4];
    #pragma unroll
    for (int j = 0; j < 4; ++j) acc[j] = (float4v){0.f, 0.f, 0.f, 0.f};

    short8 ra0, ra1, rb0, rb1;
    ra0 = *(const short8*)&A[gA];      ra1 = *(const short8*)&A[gA + 8];
    rb0 = *(const short8*)&BT[gB];     rb1 = *(const short8*)&BT[gB + 8];
    *(short8*)&As2[0][dA0] = ra0; *(short8*)&As2[0][dA1] = ra1;
    *(short8*)&Bs2[0][dA0] = rb0; *(short8*)&Bs2[0][dA1] = rb1;

    for (int it = 0; it < 8; ++it) {
        __syncthreads();
        const int cur = it & 1;
        if (it < 7) {
            const int k0 = (it + 1) * 64;
            ra0 = *(const short8*)&A[gA + k0];  ra1 = *(const short8*)&A[gA + k0 + 8];
            rb0 = *(const short8*)&BT[gB + k0]; rb1 = *(const short8*)&BT[gB + k0 + 8];
        }
        #pragma unroll
        for (int kk = 0; kk < 2; ++kk) {
            const short8 af = *(const short8*)&As2[cur][arf[kk]];
            #pragma unroll
            for (int j = 0; j < 4; ++j) {
                const short8 bf = *(const short8*)&Bs2[cur][brf[j][kk]];
                acc[j] = __builtin_amdgcn_mfma_f32_16x16x32_bf16(af, bf, acc[j], 0, 0, 0);
            }
        }
        if (it < 7) {
            const int nxt = cur ^ 1;
            *(short8*)&As2[nxt][dA0] = ra0; *(short8*)&As2[nxt][dA1] = ra1;
            *(short8*)&Bs2[nxt][dA0] = rb0; *(short8*)&Bs2[nxt][dA1] = rb1;
        }
    }

    #pragma unroll
    for (int j = 0; j < 4; ++j)
        #pragma unroll
        for (int r = 0; r < 4; ++r) {
            const int gm = row0 + wave * 16 + qd * 4 + r;
            const int gn = col0 + j * 16 + c;
            out[(size_t)gm * EMB + gn] = acc[j][r] + bias[gn];
        }
}

// ---------------------------------------------------------------------------
extern "C" void kernel_launch(void* const* d_in, const int* in_sizes, int n_in,
                              void* d_out, int out_size, void* d_ws, size_t ws_size,
                              hipStream_t stream)
{
    const float* x   = (const float*)d_in[0];
    const float* Wq  = (const float*)d_in[1];
    const float* Wk  = (const float*)d_in[2];
    const float* Wv  = (const float*)d_in[3];
    const float* Wo  = (const float*)d_in[4];
    const float* bo  = (const float*)d_in[5];
    const float* gW1 = (const float*)d_in[6];
    const float* gb1 = (const float*)d_in[7];
    const float* gg  = (const float*)d_in[8];
    const float* gbe = (const float*)d_in[9];
    const float* gW2 = (const float*)d_in[10];
    const float* gb2 = (const float*)d_in[11];
    const float* gW3 = (const float*)d_in[12];
    const float* gb3 = (const float*)d_in[13];
    const float* cW1 = (const float*)d_in[14];
    const float* cb1 = (const float*)d_in[15];
    const float* cg  = (const float*)d_in[16];
    const float* cbe = (const float*)d_in[17];
    const float* cW2 = (const float*)d_in[18];
    const float* cb2 = (const float*)d_in[19];
    const float* cW3 = (const float*)d_in[20];
    const float* cb3 = (const float*)d_in[21];
    const float* aq  = (const float*)d_in[22];
    const float* bq  = (const float*)d_in[23];
    const float* ak  = (const float*)d_in[24];
    const float* bk  = (const float*)d_in[25];
    const float* av  = (const float*)d_in[26];
    const float* bv  = (const float*)d_in[27];

    unsigned short* q_sum   = (unsigned short*)((char*)d_ws + 16384);
    unsigned short* k_sum   = q_sum   + (size_t)NROWS * EMB;
    unsigned short* v_mean  = k_sum   + (size_t)NROWS * EMB;
    unsigned short* attn_bf = v_mean  + (size_t)NROWS * EMB;
    unsigned short* WoT     = attn_bf + (size_t)NROWS * EMB;
    unsigned short* WL      = WoT     + (size_t)EMB * EMB;     // 3z x 3limb x [512][512] bf16
    unsigned short* XLp     = WL      + (size_t)9 * EMB * EMB; // 3limb x [4096][512] bf16
    double* scores          = (double*)(XLp + (size_t)3 * NROWS * EMB); // [2][4096] f64
    float* out = (float*)d_out;

    pre_kernel<<<dim3(3328), dim3(256), 0, stream>>>(
        x, gW1, gb1, gg, gbe, gW2, gb2, gW3, gb3,
        cW1, cb1, cg, cbe, cW2, cb2, cW3, cb3, scores,
        Wq, Wk, Wv, WL, XLp, Wo, WoT);

    qkv_mfma_lif_kernel<<<dim3(EMB / 64, NROWS / 128, 3), dim3(256), 0, stream>>>(
        XLp, WL, aq, bq, ak, bk, av, bv, scores, q_sum, k_sum, v_mean);

    attn_mfma_kernel<<<dim3(SEQ / 64, 8, 4), dim3(256), 0, stream>>>(
        q_sum, k_sum, v_mean, attn_bf);

    out_gemm_kernel<<<dim3(EMB / 64, NROWS / 64), dim3(256), 0, stream>>>(
        attn_bf, WoT, bo, out);
}